// Round 5
// baseline (1048.976 us; speedup 1.0000x reference)
//
#include <hip/hip_runtime.h>

// Shape: b=4, t_q=128, t_k=512, n=512, out=512. All fp32.
// Output: [out (4*128*512), probs (4*128*512)].
//
// Round-5 structure: block = (b, 2 q rows), 1024 threads = (H, u) where
// H = t>>9 picks a contraction HALF and u = t&511 picks the output index.
// Thread (H,u) computes the H-half partial of every dot product for BOTH
// q rows (keeps Q=2 register reuse of streamed rows, same L2 traffic as
// round 4), partials combine through LDS. This doubles total threads
// (262144 -> 4 waves/SIMD) to fix round-4's latency stalls (VALUBusy 30%,
// occupancy 20% at 2 waves/SIMD). Hot streams use explicit register
// double-buffering (prefetch chunk c+1 while computing chunk c).

#define BB    4
#define TQ    128
#define TK    512
#define NN    512
#define OUTSZ 512
#define CATSZ 1024
#define K2E   2.8853900817779268f   // 2*log2(e)
#define L2E   1.4426950408889634f   // log2(e)

#if __has_builtin(__builtin_amdgcn_exp2f)
#define EXP2F(x) __builtin_amdgcn_exp2f(x)
#else
#define EXP2F(x) exp2f(x)
#endif
#if __has_builtin(__builtin_amdgcn_rcpf)
#define RCPF(x) __builtin_amdgcn_rcpf(x)
#else
#define RCPF(x) (1.0f / (x))
#endif

__device__ __forceinline__ float fast_tanh(float x) {
  float e = EXP2F(x * K2E);
  return fmaf(-2.0f, RCPF(e + 1.0f), 1.0f);
}
__device__ __forceinline__ float waveRedSum(float s) {
  #pragma unroll
  for (int m = 32; m >= 1; m >>= 1) s += __shfl_xor(s, m, 64);
  return s;
}
__device__ __forceinline__ float waveRedMax(float s) {
  #pragma unroll
  for (int m = 32; m >= 1; m >>= 1) s = fmaxf(s, __shfl_xor(s, m, 64));
  return s;
}
__device__ __forceinline__ float fma4(float4 w, float4 v, float acc) {
  acc = fmaf(w.x, v.x, acc); acc = fmaf(w.y, v.y, acc);
  acc = fmaf(w.z, v.z, acc); acc = fmaf(w.w, v.w, acc);
  return acc;
}
// score micro-op, 4-wide: acc += w * rcp(exp2(fma(k, K2E, a)) + 1)
__device__ __forceinline__ float sc4(float4 w, float4 k, float4 a, float acc) {
  acc = fmaf(w.x, RCPF(EXP2F(fmaf(k.x, K2E, a.x)) + 1.0f), acc);
  acc = fmaf(w.y, RCPF(EXP2F(fmaf(k.y, K2E, a.y)) + 1.0f), acc);
  acc = fmaf(w.z, RCPF(EXP2F(fmaf(k.z, K2E, a.z)) + 1.0f), acc);
  acc = fmaf(w.w, RCPF(EXP2F(fmaf(k.w, K2E, a.w)) + 1.0f), acc);
  return acc;
}

__global__ __launch_bounds__(1024, 4)
void attn_fused(const float* __restrict__ query, const float* __restrict__ keys,
                const float* __restrict__ values, const float* __restrict__ W_q,
                const float* __restrict__ b_q, const float* __restrict__ w_att,
                const float* __restrict__ b_att, const float* __restrict__ W_out,
                const float* __restrict__ b_out,
                float* __restrict__ out, float* __restrict__ probs)
{
  __shared__ __align__(16) float qv[2][NN];       // query rows (q0,q1)
  __shared__ __align__(16) float aqc[2][NN];      // att_q * 2log2e
  __shared__ __align__(16) float wv[NN];          // w_att
  __shared__ __align__(16) float pr[2][TK];       // probs
  __shared__ __align__(16) float ctx[2][NN];      // context rows
  __shared__ __align__(16) float part[2][2][NN];  // [half][q][idx] partials
  __shared__ float redm[2][8], reds[2][8], redw[8];

  const int t    = threadIdx.x;        // 0..1023
  const int H    = t >> 9;             // contraction half 0/1
  const int u    = t & 511;            // output index
  const int wave = t >> 6;             // 0..15
  const int lane = t & 63;
  const int wq8  = wave & 7;           // wave id within the H-group

  // XCD-aware swizzle (perf heuristic only)
  const int p  = blockIdx.x;                 // 0..255
  const int b  = (p & 7) >> 1;               // 0..3
  const int qg = ((p >> 3) << 1) | (p & 1);  // 0..63
  const int qabs0 = qg * 2;

  const float batt = b_att[0];

  // ---- stage query rows + w_att ----
  if (H == 0) wv[u] = w_att[u];
  qv[H][u] = query[((size_t)(b * TQ + qabs0 + H)) * NN + u];
  __syncthreads();

  // ---- sumW (cold, once) ----
  if (H == 0) {
    float wp = waveRedSum(wv[u]);
    if (lane == 0) redw[wq8] = wp;
  }
  __syncthreads();
  const float sumW = redw[0]+redw[1]+redw[2]+redw[3]+redw[4]+redw[5]+redw[6]+redw[7];

  // ---- step 1: partial att_q.  Thread (H,u): n=u, d in [256H, 256H+256),
  //      both q rows.  Streams W_q[u] half-row (1KB) once block-wide.
  {
    const float4* wq4 = (const float4*)(W_q + (size_t)u * NN + 256 * H); // 64 f4
    const float4* x4  = (const float4*)(qv[0] + 256 * H);
    const float4* y4  = (const float4*)(qv[1] + 256 * H);
    float a0=0.f, a0b=0.f, a1=0.f, a1b=0.f;
    float4 cA=wq4[0], cB=wq4[1], cC=wq4[2], cD=wq4[3];
    #pragma unroll
    for (int c = 0; c < 16; ++c) {
      float4 nA=cA, nB=cB, nC=cC, nD=cD;
      if (c < 15) { nA=wq4[4*c+4]; nB=wq4[4*c+5]; nC=wq4[4*c+6]; nD=wq4[4*c+7]; }
      float4 xA=x4[4*c+0], xB=x4[4*c+1], xC=x4[4*c+2], xD=x4[4*c+3];
      a0  = fma4(cA, xA, a0 ); a0b = fma4(cB, xB, a0b);
      a0  = fma4(cC, xC, a0 ); a0b = fma4(cD, xD, a0b);
      float4 yA=y4[4*c+0], yB=y4[4*c+1], yC=y4[4*c+2], yD=y4[4*c+3];
      a1  = fma4(cA, yA, a1 ); a1b = fma4(cB, yB, a1b);
      a1  = fma4(cC, yC, a1 ); a1b = fma4(cD, yD, a1b);
      cA=nA; cB=nB; cC=nC; cD=nD;
    }
    part[H][0][u] = a0 + a0b;
    part[H][1][u] = a1 + a1b;
  }
  __syncthreads();
  // finalize: thread (H,u) owns q=H, n=u
  aqc[H][u] = (part[0][H][u] + part[1][H][u] + b_q[u]) * K2E;
  __syncthreads();

  // ---- step 2 (hot): partial scores.  Thread (H,u): k=u, n in
  //      [256H, 256H+256), both q rows.  Streams keys[b][u] half-row (1KB).
  {
    const float4* kr  = (const float4*)(keys + ((size_t)(b * TK) + u) * NN + 256 * H);
    const float4* a0p = (const float4*)(aqc[0] + 256 * H);
    const float4* a1p = (const float4*)(aqc[1] + 256 * H);
    const float4* w4  = (const float4*)(wv + 256 * H);
    float s0 = 0.f, s1 = 0.f;
    float4 kA=kr[0], kB=kr[1], kC=kr[2], kD=kr[3];
    #pragma unroll
    for (int c = 0; c < 16; ++c) {
      float4 nA=kA, nB=kB, nC=kC, nD=kD;
      if (c < 15) { nA=kr[4*c+4]; nB=kr[4*c+5]; nC=kr[4*c+6]; nD=kr[4*c+7]; }
      float4 wA=w4[4*c+0],  wB=w4[4*c+1],  wC=w4[4*c+2],  wD=w4[4*c+3];
      float4 aA=a0p[4*c+0], aB=a0p[4*c+1], aC=a0p[4*c+2], aD=a0p[4*c+3];
      s0 = sc4(wA, kA, aA, s0); s0 = sc4(wB, kB, aB, s0);
      s0 = sc4(wC, kC, aC, s0); s0 = sc4(wD, kD, aD, s0);
      float4 bA=a1p[4*c+0], bB=a1p[4*c+1], bC=a1p[4*c+2], bD=a1p[4*c+3];
      s1 = sc4(wA, kA, bA, s1); s1 = sc4(wB, kB, bB, s1);
      s1 = sc4(wC, kC, bC, s1); s1 = sc4(wD, kD, bD, s1);
      kA=nA; kB=nB; kC=nC; kD=nD;
    }
    part[H][0][u] = s0;
    part[H][1][u] = s1;
  }
  __syncthreads();

  // ---- softmax: thread (H,u) owns q=H, k=u.  Two independent 8-wave groups.
  float pv;
  {
    float sc = batt + sumW - 2.0f * (part[0][H][u] + part[1][H][u]);
    float m = waveRedMax(sc);
    if (lane == 0) redm[H][wq8] = m;
    __syncthreads();
    float bm = fmaxf(fmaxf(fmaxf(redm[H][0],redm[H][1]),fmaxf(redm[H][2],redm[H][3])),
                     fmaxf(fmaxf(redm[H][4],redm[H][5]),fmaxf(redm[H][6],redm[H][7])));
    float e = EXP2F((sc - bm) * L2E);
    float se = waveRedSum(e);
    if (lane == 0) reds[H][wq8] = se;
    __syncthreads();
    float bs = reds[H][0]+reds[H][1]+reds[H][2]+reds[H][3]
             + reds[H][4]+reds[H][5]+reds[H][6]+reds[H][7];
    pv = e * RCPF(bs);
    pr[H][u] = pv;
    probs[((size_t)(b * TQ + qabs0 + H)) * TK + u] = pv;
  }
  __syncthreads();

  // ---- step 4: partial context.  Thread (H,u): n=u, k in [256H, 256H+256),
  //      both q rows.  values column loads are lane-coalesced.
  {
    const float* vcol = values + ((size_t)(b * TK) + 256 * H) * NN + u;
    const float4* p0 = (const float4*)(pr[0] + 256 * H);
    const float4* p1 = (const float4*)(pr[1] + 256 * H);
    float c0a=0.f, c0b=0.f, c1a=0.f, c1b=0.f;
    #pragma unroll 4
    for (int k = 0; k < 256; k += 8) {
      float v0 = vcol[(size_t)(k+0)*NN]; float v1 = vcol[(size_t)(k+1)*NN];
      float v2 = vcol[(size_t)(k+2)*NN]; float v3 = vcol[(size_t)(k+3)*NN];
      float v4 = vcol[(size_t)(k+4)*NN]; float v5 = vcol[(size_t)(k+5)*NN];
      float v6 = vcol[(size_t)(k+6)*NN]; float v7 = vcol[(size_t)(k+7)*NN];
      float4 pA = p0[k>>2], pB = p0[(k>>2)+1];
      float4 qA = p1[k>>2], qB = p1[(k>>2)+1];
      c0a = fmaf(pA.x,v0,c0a); c0a = fmaf(pA.y,v1,c0a);
      c0b = fmaf(pA.z,v2,c0b); c0b = fmaf(pA.w,v3,c0b);
      c0a = fmaf(pB.x,v4,c0a); c0a = fmaf(pB.y,v5,c0a);
      c0b = fmaf(pB.z,v6,c0b); c0b = fmaf(pB.w,v7,c0b);
      c1a = fmaf(qA.x,v0,c1a); c1a = fmaf(qA.y,v1,c1a);
      c1b = fmaf(qA.z,v2,c1b); c1b = fmaf(qA.w,v3,c1b);
      c1a = fmaf(qB.x,v4,c1a); c1a = fmaf(qB.y,v5,c1a);
      c1b = fmaf(qB.z,v6,c1b); c1b = fmaf(qB.w,v7,c1b);
    }
    part[H][0][u] = c0a + c0b;
    part[H][1][u] = c1a + c1b;
  }
  __syncthreads();
  ctx[H][u] = part[0][H][u] + part[1][H][u];
  __syncthreads();

  // ---- step 5: partial output.  Thread (H,u): o=u, c-half H (H=0: query
  //      part of concat, H=1: context part), both q rows.  Streams
  //      W_out[u] half-row (2KB) once block-wide.
  {
    const float4* wo = (const float4*)(W_out + (size_t)u * CATSZ + 512 * H); // 128 f4
    const float4* x4 = (H == 0) ? (const float4*)qv[0] : (const float4*)ctx[0];
    const float4* y4 = (H == 0) ? (const float4*)qv[1] : (const float4*)ctx[1];
    float o0=0.f, o0b=0.f, o1=0.f, o1b=0.f;
    float4 cA=wo[0], cB=wo[1], cC=wo[2], cD=wo[3];
    #pragma unroll
    for (int c = 0; c < 32; ++c) {
      float4 nA=cA, nB=cB, nC=cC, nD=cD;
      if (c < 31) { nA=wo[4*c+4]; nB=wo[4*c+5]; nC=wo[4*c+6]; nD=wo[4*c+7]; }
      float4 xA=x4[4*c+0], xB=x4[4*c+1], xC=x4[4*c+2], xD=x4[4*c+3];
      o0  = fma4(cA, xA, o0 ); o0b = fma4(cB, xB, o0b);
      o0  = fma4(cC, xC, o0 ); o0b = fma4(cD, xD, o0b);
      float4 yA=y4[4*c+0], yB=y4[4*c+1], yC=y4[4*c+2], yD=y4[4*c+3];
      o1  = fma4(cA, yA, o1 ); o1b = fma4(cB, yB, o1b);
      o1  = fma4(cC, yC, o1 ); o1b = fma4(cD, yD, o1b);
      cA=nA; cB=nB; cC=nC; cD=nD;
    }
    part[H][0][u] = o0 + o0b;
    part[H][1][u] = o1 + o1b;
  }
  __syncthreads();
  // finalize: thread (H,u) owns q=H, o=u
  {
    float oo = part[0][H][u] + part[1][H][u] + b_out[u];
    out[((size_t)(b * TQ + qabs0 + H)) * OUTSZ + u] = fast_tanh(oo);
  }
}

extern "C" void kernel_launch(void* const* d_in, const int* in_sizes, int n_in,
                              void* d_out, int out_size, void* d_ws, size_t ws_size,
                              hipStream_t stream) {
  const float* query = (const float*)d_in[0];
  const float* keys  = (const float*)d_in[1];
  const float* vals  = (const float*)d_in[2];
  const float* W_q   = (const float*)d_in[3];
  const float* b_q   = (const float*)d_in[4];
  const float* w_att = (const float*)d_in[5];
  const float* b_att = (const float*)d_in[6];
  const float* W_out = (const float*)d_in[7];
  const float* b_out = (const float*)d_in[8];

  float* out   = (float*)d_out;
  float* probs = out + (size_t)BB * TQ * OUTSZ;

  attn_fused<<<dim3(BB * TQ / 2), dim3(1024), 0, stream>>>(
      query, keys, vals, W_q, b_q, w_att, b_att, W_out, b_out, out, probs);
}

// Round 6
// 214.243 us; speedup vs baseline: 4.8962x; 4.8962x over previous
//
#include <hip/hip_runtime.h>

// Shape: b=4, t_q=128, t_k=512, n=512, out=512. All fp32.
// Output: [out (4*128*512), probs (4*128*512)].
//
// Round-6: round-5 H-split structure (1024 thr = contraction half H x
// output index u; Q=2 q-row register reuse; 256 blocks -> 4 waves/SIMD)
// but with round-4 codegen style: #pragma unroll 2, straight load+fma
// bodies, NO manual prefetch rotation.  Round-5 lesson: full unroll +
// 8 live float4 rotation buffers => register spill (WRITE_SIZE 1.28 GB,
// 7x regression).  launch_bounds(1024,4) caps VGPR at 128.

#define BB    4
#define TQ    128
#define TK    512
#define NN    512
#define OUTSZ 512
#define CATSZ 1024
#define K2E   2.8853900817779268f   // 2*log2(e)
#define L2E   1.4426950408889634f   // log2(e)

#if __has_builtin(__builtin_amdgcn_exp2f)
#define EXP2F(x) __builtin_amdgcn_exp2f(x)
#else
#define EXP2F(x) exp2f(x)
#endif
#if __has_builtin(__builtin_amdgcn_rcpf)
#define RCPF(x) __builtin_amdgcn_rcpf(x)
#else
#define RCPF(x) (1.0f / (x))
#endif

__device__ __forceinline__ float fast_tanh(float x) {
  float e = EXP2F(x * K2E);
  return fmaf(-2.0f, RCPF(e + 1.0f), 1.0f);
}
__device__ __forceinline__ float waveRedSum(float s) {
  #pragma unroll
  for (int m = 32; m >= 1; m >>= 1) s += __shfl_xor(s, m, 64);
  return s;
}
__device__ __forceinline__ float waveRedMax(float s) {
  #pragma unroll
  for (int m = 32; m >= 1; m >>= 1) s = fmaxf(s, __shfl_xor(s, m, 64));
  return s;
}
__device__ __forceinline__ float fma4(float4 w, float4 v, float acc) {
  acc = fmaf(w.x, v.x, acc); acc = fmaf(w.y, v.y, acc);
  acc = fmaf(w.z, v.z, acc); acc = fmaf(w.w, v.w, acc);
  return acc;
}
// score micro-op, 4-wide: acc += w * rcp(exp2(fma(k, K2E, a)) + 1)
__device__ __forceinline__ float sc4(float4 w, float4 k, float4 a, float acc) {
  acc = fmaf(w.x, RCPF(EXP2F(fmaf(k.x, K2E, a.x)) + 1.0f), acc);
  acc = fmaf(w.y, RCPF(EXP2F(fmaf(k.y, K2E, a.y)) + 1.0f), acc);
  acc = fmaf(w.z, RCPF(EXP2F(fmaf(k.z, K2E, a.z)) + 1.0f), acc);
  acc = fmaf(w.w, RCPF(EXP2F(fmaf(k.w, K2E, a.w)) + 1.0f), acc);
  return acc;
}

__global__ __launch_bounds__(1024, 4)
void attn_fused(const float* __restrict__ query, const float* __restrict__ keys,
                const float* __restrict__ values, const float* __restrict__ W_q,
                const float* __restrict__ b_q, const float* __restrict__ w_att,
                const float* __restrict__ b_att, const float* __restrict__ W_out,
                const float* __restrict__ b_out,
                float* __restrict__ out, float* __restrict__ probs)
{
  __shared__ __align__(16) float qv[2][NN];       // query rows (q0,q1)
  __shared__ __align__(16) float aqc[2][NN];      // att_q * 2log2e
  __shared__ __align__(16) float wv[NN];          // w_att
  __shared__ __align__(16) float pr[2][TK];       // probs
  __shared__ __align__(16) float ctx[2][NN];      // context rows
  __shared__ __align__(16) float part[2][2][NN];  // [half][q][idx] partials
  __shared__ float redm[2][8], reds[2][8], redw[8];

  const int t    = threadIdx.x;        // 0..1023
  const int H    = t >> 9;             // contraction half 0/1 (wave-uniform)
  const int u    = t & 511;            // output index
  const int wave = t >> 6;             // 0..15
  const int lane = t & 63;
  const int wq8  = wave & 7;           // wave id within the H-group

  // XCD-aware swizzle (perf heuristic only)
  const int p  = blockIdx.x;                 // 0..255
  const int b  = (p & 7) >> 1;               // 0..3
  const int qg = ((p >> 3) << 1) | (p & 1);  // 0..63
  const int qabs0 = qg * 2;

  const float batt = b_att[0];

  // ---- stage query rows + w_att ----
  if (H == 0) wv[u] = w_att[u];
  qv[H][u] = query[((size_t)(b * TQ + qabs0 + H)) * NN + u];
  __syncthreads();

  // ---- sumW (cold, once) ----
  if (H == 0) {
    float wp = waveRedSum(wv[u]);
    if (lane == 0) redw[wq8] = wp;
  }
  __syncthreads();
  const float sumW = redw[0]+redw[1]+redw[2]+redw[3]+redw[4]+redw[5]+redw[6]+redw[7];

  // ---- step 1: partial att_q.  Thread (H,u): n=u, d in [256H, 256H+256),
  //      both q rows.  Streams W_q[u] half-row (1KB) once block-wide.
  {
    const float4* wq4 = (const float4*)(W_q + (size_t)u * NN + 256 * H); // 64 f4
    const float4* x4  = (const float4*)(qv[0] + 256 * H);
    const float4* y4  = (const float4*)(qv[1] + 256 * H);
    float a0=0.f, a0b=0.f, a1=0.f, a1b=0.f;
    #pragma unroll 2
    for (int c = 0; c < 16; ++c) {
      float4 wA=wq4[4*c+0], wB=wq4[4*c+1], wC=wq4[4*c+2], wD=wq4[4*c+3];
      float4 xA=x4[4*c+0], xB=x4[4*c+1], xC=x4[4*c+2], xD=x4[4*c+3];
      a0  = fma4(wA, xA, a0 ); a0b = fma4(wB, xB, a0b);
      a0  = fma4(wC, xC, a0 ); a0b = fma4(wD, xD, a0b);
      float4 yA=y4[4*c+0], yB=y4[4*c+1], yC=y4[4*c+2], yD=y4[4*c+3];
      a1  = fma4(wA, yA, a1 ); a1b = fma4(wB, yB, a1b);
      a1  = fma4(wC, yC, a1 ); a1b = fma4(wD, yD, a1b);
    }
    part[H][0][u] = a0 + a0b;
    part[H][1][u] = a1 + a1b;
  }
  __syncthreads();
  // finalize: thread (H,u) owns q=H, n=u
  aqc[H][u] = (part[0][H][u] + part[1][H][u] + b_q[u]) * K2E;
  __syncthreads();

  // ---- step 2 (hot): partial scores.  Thread (H,u): k=u, n in
  //      [256H, 256H+256), both q rows.  Streams keys[b][u] half-row (1KB).
  {
    const float4* kr  = (const float4*)(keys + ((size_t)(b * TK) + u) * NN + 256 * H);
    const float4* a0p = (const float4*)(aqc[0] + 256 * H);
    const float4* a1p = (const float4*)(aqc[1] + 256 * H);
    const float4* w4  = (const float4*)(wv + 256 * H);
    float s0 = 0.f, s1 = 0.f;
    #pragma unroll 2
    for (int c = 0; c < 16; ++c) {
      float4 kA=kr[4*c+0], kB=kr[4*c+1], kC=kr[4*c+2], kD=kr[4*c+3];
      float4 wA=w4[4*c+0],  wB=w4[4*c+1],  wC=w4[4*c+2],  wD=w4[4*c+3];
      float4 aA=a0p[4*c+0], aB=a0p[4*c+1], aC=a0p[4*c+2], aD=a0p[4*c+3];
      s0 = sc4(wA, kA, aA, s0); s0 = sc4(wB, kB, aB, s0);
      s0 = sc4(wC, kC, aC, s0); s0 = sc4(wD, kD, aD, s0);
      float4 bA=a1p[4*c+0], bB=a1p[4*c+1], bC=a1p[4*c+2], bD=a1p[4*c+3];
      s1 = sc4(wA, kA, bA, s1); s1 = sc4(wB, kB, bB, s1);
      s1 = sc4(wC, kC, bC, s1); s1 = sc4(wD, kD, bD, s1);
    }
    part[H][0][u] = s0;
    part[H][1][u] = s1;
  }
  __syncthreads();

  // ---- softmax: thread (H,u) owns q=H, k=u.  Two independent 8-wave groups.
  float pv;
  {
    float sc = batt + sumW - 2.0f * (part[0][H][u] + part[1][H][u]);
    float m = waveRedMax(sc);
    if (lane == 0) redm[H][wq8] = m;
    __syncthreads();
    float bm = fmaxf(fmaxf(fmaxf(redm[H][0],redm[H][1]),fmaxf(redm[H][2],redm[H][3])),
                     fmaxf(fmaxf(redm[H][4],redm[H][5]),fmaxf(redm[H][6],redm[H][7])));
    float e = EXP2F((sc - bm) * L2E);
    float se = waveRedSum(e);
    if (lane == 0) reds[H][wq8] = se;
    __syncthreads();
    float bs = reds[H][0]+reds[H][1]+reds[H][2]+reds[H][3]
             + reds[H][4]+reds[H][5]+reds[H][6]+reds[H][7];
    pv = e * RCPF(bs);
    pr[H][u] = pv;
    probs[((size_t)(b * TQ + qabs0 + H)) * TK + u] = pv;
  }
  __syncthreads();

  // ---- step 4: partial context.  Thread (H,u): n=u, k in [256H, 256H+256),
  //      both q rows.  values column loads are lane-coalesced.
  {
    const float* vcol = values + ((size_t)(b * TK) + 256 * H) * NN + u;
    const float4* p0 = (const float4*)(pr[0] + 256 * H);
    const float4* p1 = (const float4*)(pr[1] + 256 * H);
    float c0a=0.f, c0b=0.f, c1a=0.f, c1b=0.f;
    #pragma unroll 2
    for (int k = 0; k < 256; k += 8) {
      float v0 = vcol[(size_t)(k+0)*NN]; float v1 = vcol[(size_t)(k+1)*NN];
      float v2 = vcol[(size_t)(k+2)*NN]; float v3 = vcol[(size_t)(k+3)*NN];
      float v4 = vcol[(size_t)(k+4)*NN]; float v5 = vcol[(size_t)(k+5)*NN];
      float v6 = vcol[(size_t)(k+6)*NN]; float v7 = vcol[(size_t)(k+7)*NN];
      float4 pA = p0[k>>2], pB = p0[(k>>2)+1];
      float4 qA = p1[k>>2], qB = p1[(k>>2)+1];
      c0a = fmaf(pA.x,v0,c0a); c0a = fmaf(pA.y,v1,c0a);
      c0b = fmaf(pA.z,v2,c0b); c0b = fmaf(pA.w,v3,c0b);
      c0a = fmaf(pB.x,v4,c0a); c0a = fmaf(pB.y,v5,c0a);
      c0b = fmaf(pB.z,v6,c0b); c0b = fmaf(pB.w,v7,c0b);
      c1a = fmaf(qA.x,v0,c1a); c1a = fmaf(qA.y,v1,c1a);
      c1b = fmaf(qA.z,v2,c1b); c1b = fmaf(qA.w,v3,c1b);
      c1a = fmaf(qB.x,v4,c1a); c1a = fmaf(qB.y,v5,c1a);
      c1b = fmaf(qB.z,v6,c1b); c1b = fmaf(qB.w,v7,c1b);
    }
    part[H][0][u] = c0a + c0b;
    part[H][1][u] = c1a + c1b;
  }
  __syncthreads();
  ctx[H][u] = part[0][H][u] + part[1][H][u];
  __syncthreads();

  // ---- step 5: partial output.  Thread (H,u): o=u, c-half H (H=0: query
  //      part of concat, H=1: context part), both q rows.  Streams
  //      W_out[u] half-row (2KB) once block-wide.
  {
    const float4* wo = (const float4*)(W_out + (size_t)u * CATSZ + 512 * H); // 128 f4
    const float4* x4 = (H == 0) ? (const float4*)qv[0] : (const float4*)ctx[0];
    const float4* y4 = (H == 0) ? (const float4*)qv[1] : (const float4*)ctx[1];
    float o0=0.f, o0b=0.f, o1=0.f, o1b=0.f;
    #pragma unroll 2
    for (int c = 0; c < 32; ++c) {
      float4 wA=wo[4*c+0], wB=wo[4*c+1], wC=wo[4*c+2], wD=wo[4*c+3];
      float4 xA=x4[4*c+0], xB=x4[4*c+1], xC=x4[4*c+2], xD=x4[4*c+3];
      o0  = fma4(wA, xA, o0 ); o0b = fma4(wB, xB, o0b);
      o0  = fma4(wC, xC, o0 ); o0b = fma4(wD, xD, o0b);
      float4 yA=y4[4*c+0], yB=y4[4*c+1], yC=y4[4*c+2], yD=y4[4*c+3];
      o1  = fma4(wA, yA, o1 ); o1b = fma4(wB, yB, o1b);
      o1  = fma4(wC, yC, o1 ); o1b = fma4(wD, yD, o1b);
    }
    part[H][0][u] = o0 + o0b;
    part[H][1][u] = o1 + o1b;
  }
  __syncthreads();
  // finalize: thread (H,u) owns q=H, o=u
  {
    float oo = part[0][H][u] + part[1][H][u] + b_out[u];
    out[((size_t)(b * TQ + qabs0 + H)) * OUTSZ + u] = fast_tanh(oo);
  }
}

extern "C" void kernel_launch(void* const* d_in, const int* in_sizes, int n_in,
                              void* d_out, int out_size, void* d_ws, size_t ws_size,
                              hipStream_t stream) {
  const float* query = (const float*)d_in[0];
  const float* keys  = (const float*)d_in[1];
  const float* vals  = (const float*)d_in[2];
  const float* W_q   = (const float*)d_in[3];
  const float* b_q   = (const float*)d_in[4];
  const float* b_att = (const float*)d_in[6];
  const float* w_att = (const float*)d_in[5];
  const float* W_out = (const float*)d_in[7];
  const float* b_out = (const float*)d_in[8];

  float* out   = (float*)d_out;
  float* probs = out + (size_t)BB * TQ * OUTSZ;

  attn_fused<<<dim3(BB * TQ / 2), dim3(1024), 0, stream>>>(
      query, keys, vals, W_q, b_q, w_att, b_att, W_out, b_out, out, probs);
}

// Round 7
// 155.983 us; speedup vs baseline: 6.7249x; 1.3735x over previous
//
#include <hip/hip_runtime.h>

// Shape: b=4, t_q=128, t_k=512, n=512, out=512. All fp32.
// Output: [out (4*128*512), probs (4*128*512)].
//
// Round-7: round-6 analysis showed a shared-resource plateau (~150us,
// VALUBusy ~30% invariant to occupancy 20%->46%): per-thread private row
// streams make each wave load touch 64 distinct cache lines (2KB lane
// stride) -> TA/TCP tag-pipe serialization. Fix: pack kernel transposes
// keys (pre-scaled by 2log2e), W_q, W_out into d_ws; main kernel reads
// them coalesced (lane-consecutive addresses), with per-n shared operands
// broadcast from LDS float4/float2 packs. Fallback to round-6 kernel if
// ws_size < 7 MB.

#define BB    4
#define TQ    128
#define TK    512
#define NN    512
#define OUTSZ 512
#define CATSZ 1024
#define K2E   2.8853900817779268f   // 2*log2(e)
#define L2E   1.4426950408889634f   // log2(e)
#define MAT   262144                // 512*512 floats
#define WS_FLOATS (7 * MAT)         // keysT(4) + W_qT(1) + W_outT(2)

#if __has_builtin(__builtin_amdgcn_exp2f)
#define EXP2F(x) __builtin_amdgcn_exp2f(x)
#else
#define EXP2F(x) exp2f(x)
#endif
#if __has_builtin(__builtin_amdgcn_rcpf)
#define RCPF(x) __builtin_amdgcn_rcpf(x)
#else
#define RCPF(x) (1.0f / (x))
#endif

__device__ __forceinline__ float fast_tanh(float x) {
  float e = EXP2F(x * K2E);
  return fmaf(-2.0f, RCPF(e + 1.0f), 1.0f);
}
__device__ __forceinline__ float waveRedSum(float s) {
  #pragma unroll
  for (int m = 32; m >= 1; m >>= 1) s += __shfl_xor(s, m, 64);
  return s;
}
__device__ __forceinline__ float waveRedMax(float s) {
  #pragma unroll
  for (int m = 32; m >= 1; m >>= 1) s = fmaxf(s, __shfl_xor(s, m, 64));
  return s;
}
__device__ __forceinline__ float fma4(float4 w, float4 v, float acc) {
  acc = fmaf(w.x, v.x, acc); acc = fmaf(w.y, v.y, acc);
  acc = fmaf(w.z, v.z, acc); acc = fmaf(w.w, v.w, acc);
  return acc;
}

// ---------------- pack kernel: transpose streamed operands into ws ----------
// ws layout (floats): [0,4*MAT) keysT[b][n][k] * K2E; [4*MAT,5*MAT) W_qT[d][n];
//                     [5*MAT,7*MAT) W_outT[c][o].
__global__ __launch_bounds__(256)
void pack_kernel(const float* __restrict__ keys, const float* __restrict__ W_q,
                 const float* __restrict__ W_out, float* __restrict__ ws)
{
  __shared__ float tile[32][33];
  const int idx = blockIdx.x;
  const float* src; float* dst; int M, N; float scale; int by, bx;
  if (idx < 1024) {                       // keys: 4 x (512x512)
    int b = idx >> 8, r = idx & 255;
    by = r >> 4; bx = r & 15;
    src = keys + (size_t)b * MAT; dst = ws + (size_t)b * MAT;
    M = 512; N = 512; scale = K2E;
  } else if (idx < 1280) {                // W_q 512x512
    int r = idx - 1024; by = r >> 4; bx = r & 15;
    src = W_q; dst = ws + (size_t)4 * MAT; M = 512; N = 512; scale = 1.0f;
  } else {                                // W_out 512x1024 -> 1024x512
    int r = idx - 1280; by = r >> 5; bx = r & 31;
    src = W_out; dst = ws + (size_t)5 * MAT; M = 512; N = 1024; scale = 1.0f;
  }
  const int tx = threadIdx.x & 31, ty = threadIdx.x >> 5;   // 32x8
  #pragma unroll
  for (int i = 0; i < 32; i += 8)
    tile[ty + i][tx] = src[(size_t)(by * 32 + ty + i) * N + bx * 32 + tx] * scale;
  __syncthreads();
  #pragma unroll
  for (int i = 0; i < 32; i += 8)
    dst[(size_t)(bx * 32 + ty + i) * M + by * 32 + tx] = tile[tx][ty + i];
}

// ---------------- main kernel (coalesced) ----------------------------------
__global__ __launch_bounds__(1024, 4)
void attn_main(const float* __restrict__ query, const float* __restrict__ values,
               const float* __restrict__ b_q, const float* __restrict__ w_att,
               const float* __restrict__ b_att, const float* __restrict__ b_out,
               const float* __restrict__ ws,
               float* __restrict__ out, float* __restrict__ probs)
{
  __shared__ __align__(16) float2 qpack[NN];     // {q0[d], q1[d]}
  __shared__ __align__(16) float4 paw[NN];       // {aq0*K2E, aq1*K2E, w, pad}
  __shared__ __align__(16) float2 ctxp[NN];      // {ctx0[n], ctx1[n]}
  __shared__ __align__(16) float  wv[NN];        // w_att
  __shared__ __align__(16) float  pr[2][TK];     // probs rows
  __shared__ __align__(16) float  part[2][2][NN];// [half][q][idx]
  __shared__ float redm[2][8], reds2[2][8], redw[8];

  const float* wsKeys = ws;
  const float* wsWq   = ws + (size_t)4 * MAT;
  const float* wsWout = ws + (size_t)5 * MAT;

  const int t    = threadIdx.x;        // 0..1023
  const int H    = t >> 9;             // contraction half (wave-uniform)
  const int u    = t & 511;            // output index
  const int wave = t >> 6, lane = t & 63;
  const int wq8  = wave & 7;

  const int p  = blockIdx.x;                 // 0..255 (XCD swizzle)
  const int b  = (p & 7) >> 1;
  const int qg = ((p >> 3) << 1) | (p & 1);
  const int qabs0 = qg * 2;

  const float batt = b_att[0];

  // ---- stage: query pack + w_att ----
  float w_own = 0.f;
  if (H == 0) {
    float q0 = query[((size_t)(b * TQ + qabs0 + 0)) * NN + u];
    float q1 = query[((size_t)(b * TQ + qabs0 + 1)) * NN + u];
    qpack[u] = make_float2(q0, q1);
  } else {
    w_own = w_att[u];
    wv[u] = w_own;
  }
  __syncthreads();

  // sumW (cold, once)
  if (H == 1) {
    float wp = waveRedSum(w_own);
    if (lane == 0) redw[wq8] = wp;
  }
  __syncthreads();
  const float sumW = redw[0]+redw[1]+redw[2]+redw[3]+redw[4]+redw[5]+redw[6]+redw[7];

  // ---- step 1: att_q partials.  Thread (H,u): n=u, d in [256H,256H+256).
  //      W_qT[d][u] coalesced; qpack[d] LDS broadcast.
  {
    const float* wq = wsWq + (size_t)(256 * H) * 512 + u;
    float a0 = 0.f, a1 = 0.f;
    #pragma unroll 8
    for (int j = 0; j < 256; ++j) {
      float wt = wq[(size_t)j * 512];
      float2 qp = qpack[256 * H + j];
      a0 = fmaf(wt, qp.x, a0); a1 = fmaf(wt, qp.y, a1);
    }
    part[H][0][u] = a0; part[H][1][u] = a1;
  }
  __syncthreads();
  {
    float aq = (part[0][H][u] + part[1][H][u] + b_q[u]) * K2E;
    if (H == 0) { paw[u].x = aq; paw[u].z = wv[u]; paw[u].w = 0.f; }
    else        { paw[u].y = aq; }
  }
  __syncthreads();

  // ---- step 2 (hot): score partials.  Thread (H,u): k=u, n in [256H,+256).
  //      keysT (pre-scaled) coalesced; paw[n] LDS b128 broadcast.
  {
    const float* kt = wsKeys + (size_t)b * MAT + (size_t)(256 * H) * 512 + u;
    float s0 = 0.f, s1 = 0.f;
    #pragma unroll 8
    for (int j = 0; j < 256; ++j) {
      float kv = kt[(size_t)j * 512];
      float4 pw = paw[256 * H + j];
      float e0 = EXP2F(kv + pw.x);
      float e1 = EXP2F(kv + pw.y);
      s0 = fmaf(pw.z, RCPF(e0 + 1.0f), s0);
      s1 = fmaf(pw.z, RCPF(e1 + 1.0f), s1);
    }
    part[H][0][u] = s0; part[H][1][u] = s1;
  }
  __syncthreads();

  // ---- softmax: thread (H,u) owns q=H, k=u.
  {
    float sc = batt + sumW - 2.0f * (part[0][H][u] + part[1][H][u]);
    float m = waveRedMax(sc);
    if (lane == 0) redm[H][wq8] = m;
    __syncthreads();
    float bm = fmaxf(fmaxf(fmaxf(redm[H][0],redm[H][1]),fmaxf(redm[H][2],redm[H][3])),
                     fmaxf(fmaxf(redm[H][4],redm[H][5]),fmaxf(redm[H][6],redm[H][7])));
    float e = EXP2F((sc - bm) * L2E);
    float se = waveRedSum(e);
    if (lane == 0) reds2[H][wq8] = se;
    __syncthreads();
    float bs = reds2[H][0]+reds2[H][1]+reds2[H][2]+reds2[H][3]
             + reds2[H][4]+reds2[H][5]+reds2[H][6]+reds2[H][7];
    float pv = e * RCPF(bs);
    pr[H][u] = pv;
    probs[((size_t)(b * TQ + qabs0 + H)) * TK + u] = pv;
  }
  __syncthreads();

  // ---- step 4: context partials.  Thread (H,u): n=u, k in [256H,+256).
  //      values columns already coalesced; pr LDS b128 broadcast.
  {
    const float* vcol = values + ((size_t)(b * TK) + 256 * H) * NN + u;
    const float4* p0 = (const float4*)(pr[0] + 256 * H);
    const float4* p1 = (const float4*)(pr[1] + 256 * H);
    float c0a=0.f, c0b=0.f, c1a=0.f, c1b=0.f;
    #pragma unroll 2
    for (int k = 0; k < 256; k += 8) {
      float v0 = vcol[(size_t)(k+0)*NN]; float v1 = vcol[(size_t)(k+1)*NN];
      float v2 = vcol[(size_t)(k+2)*NN]; float v3 = vcol[(size_t)(k+3)*NN];
      float v4 = vcol[(size_t)(k+4)*NN]; float v5 = vcol[(size_t)(k+5)*NN];
      float v6 = vcol[(size_t)(k+6)*NN]; float v7 = vcol[(size_t)(k+7)*NN];
      float4 pA = p0[k>>2], pB = p0[(k>>2)+1];
      float4 qA = p1[k>>2], qB = p1[(k>>2)+1];
      c0a = fmaf(pA.x,v0,c0a); c0a = fmaf(pA.y,v1,c0a);
      c0b = fmaf(pA.z,v2,c0b); c0b = fmaf(pA.w,v3,c0b);
      c0a = fmaf(pB.x,v4,c0a); c0a = fmaf(pB.y,v5,c0a);
      c0b = fmaf(pB.z,v6,c0b); c0b = fmaf(pB.w,v7,c0b);
      c1a = fmaf(qA.x,v0,c1a); c1a = fmaf(qA.y,v1,c1a);
      c1b = fmaf(qA.z,v2,c1b); c1b = fmaf(qA.w,v3,c1b);
      c1a = fmaf(qB.x,v4,c1a); c1a = fmaf(qB.y,v5,c1a);
      c1b = fmaf(qB.z,v6,c1b); c1b = fmaf(qB.w,v7,c1b);
    }
    part[H][0][u] = c0a + c0b; part[H][1][u] = c1a + c1b;
  }
  __syncthreads();
  {
    float cv = part[0][H][u] + part[1][H][u];
    if (H == 0) ctxp[u].x = cv; else ctxp[u].y = cv;
  }
  __syncthreads();

  // ---- step 5: out partials.  Thread (H,u): o=u, c in [512H,+512).
  //      W_outT[c][u] coalesced; cat pack LDS b64 broadcast.
  {
    const float* wo = wsWout + (size_t)(512 * H) * 512 + u;
    const float2* cp = (H == 0) ? qpack : ctxp;
    float o0 = 0.f, o1 = 0.f;
    #pragma unroll 8
    for (int j = 0; j < 512; ++j) {
      float wt = wo[(size_t)j * 512];
      float2 c2 = cp[j];
      o0 = fmaf(wt, c2.x, o0); o1 = fmaf(wt, c2.y, o1);
    }
    part[H][0][u] = o0; part[H][1][u] = o1;
  }
  __syncthreads();
  {
    float oo = part[0][H][u] + part[1][H][u] + b_out[u];
    out[((size_t)(b * TQ + qabs0 + H)) * OUTSZ + u] = fast_tanh(oo);
  }
}

// ---------------- round-6 fallback (used only if ws too small) --------------
__device__ __forceinline__ float sc4f(float4 w, float4 k, float4 a, float acc) {
  acc = fmaf(w.x, RCPF(EXP2F(fmaf(k.x, K2E, a.x)) + 1.0f), acc);
  acc = fmaf(w.y, RCPF(EXP2F(fmaf(k.y, K2E, a.y)) + 1.0f), acc);
  acc = fmaf(w.z, RCPF(EXP2F(fmaf(k.z, K2E, a.z)) + 1.0f), acc);
  acc = fmaf(w.w, RCPF(EXP2F(fmaf(k.w, K2E, a.w)) + 1.0f), acc);
  return acc;
}

__global__ __launch_bounds__(1024, 4)
void attn_fallback(const float* __restrict__ query, const float* __restrict__ keys,
                   const float* __restrict__ values, const float* __restrict__ W_q,
                   const float* __restrict__ b_q, const float* __restrict__ w_att,
                   const float* __restrict__ b_att, const float* __restrict__ W_out,
                   const float* __restrict__ b_out,
                   float* __restrict__ out, float* __restrict__ probs)
{
  __shared__ __align__(16) float qv[2][NN];
  __shared__ __align__(16) float aqc[2][NN];
  __shared__ __align__(16) float wv[NN];
  __shared__ __align__(16) float pr[2][TK];
  __shared__ __align__(16) float ctx[2][NN];
  __shared__ __align__(16) float part[2][2][NN];
  __shared__ float redm[2][8], reds[2][8], redw[8];

  const int t = threadIdx.x, H = t >> 9, u = t & 511;
  const int wave = t >> 6, lane = t & 63, wq8 = wave & 7;
  const int p = blockIdx.x, b = (p & 7) >> 1;
  const int qg = ((p >> 3) << 1) | (p & 1), qabs0 = qg * 2;
  const float batt = b_att[0];

  if (H == 0) wv[u] = w_att[u];
  qv[H][u] = query[((size_t)(b * TQ + qabs0 + H)) * NN + u];
  __syncthreads();
  if (H == 0) {
    float wp = waveRedSum(wv[u]);
    if (lane == 0) redw[wq8] = wp;
  }
  __syncthreads();
  const float sumW = redw[0]+redw[1]+redw[2]+redw[3]+redw[4]+redw[5]+redw[6]+redw[7];

  {
    const float4* wq4 = (const float4*)(W_q + (size_t)u * NN + 256 * H);
    const float4* x4  = (const float4*)(qv[0] + 256 * H);
    const float4* y4  = (const float4*)(qv[1] + 256 * H);
    float a0=0.f, a0b=0.f, a1=0.f, a1b=0.f;
    #pragma unroll 2
    for (int c = 0; c < 16; ++c) {
      float4 wA=wq4[4*c+0], wB=wq4[4*c+1], wC=wq4[4*c+2], wD=wq4[4*c+3];
      float4 xA=x4[4*c+0], xB=x4[4*c+1], xC=x4[4*c+2], xD=x4[4*c+3];
      a0 = fma4(wA,xA,a0); a0b = fma4(wB,xB,a0b);
      a0 = fma4(wC,xC,a0); a0b = fma4(wD,xD,a0b);
      float4 yA=y4[4*c+0], yB=y4[4*c+1], yC=y4[4*c+2], yD=y4[4*c+3];
      a1 = fma4(wA,yA,a1); a1b = fma4(wB,yB,a1b);
      a1 = fma4(wC,yC,a1); a1b = fma4(wD,yD,a1b);
    }
    part[H][0][u] = a0 + a0b; part[H][1][u] = a1 + a1b;
  }
  __syncthreads();
  aqc[H][u] = (part[0][H][u] + part[1][H][u] + b_q[u]) * K2E;
  __syncthreads();

  {
    const float4* kr  = (const float4*)(keys + ((size_t)(b * TK) + u) * NN + 256 * H);
    const float4* a0p = (const float4*)(aqc[0] + 256 * H);
    const float4* a1p = (const float4*)(aqc[1] + 256 * H);
    const float4* w4  = (const float4*)(wv + 256 * H);
    float s0 = 0.f, s1 = 0.f;
    #pragma unroll 2
    for (int c = 0; c < 16; ++c) {
      float4 kA=kr[4*c+0], kB=kr[4*c+1], kC=kr[4*c+2], kD=kr[4*c+3];
      float4 wA=w4[4*c+0], wB=w4[4*c+1], wC=w4[4*c+2], wD=w4[4*c+3];
      float4 aA=a0p[4*c+0], aB=a0p[4*c+1], aC=a0p[4*c+2], aD=a0p[4*c+3];
      s0 = sc4f(wA,kA,aA,s0); s0 = sc4f(wB,kB,aB,s0);
      s0 = sc4f(wC,kC,aC,s0); s0 = sc4f(wD,kD,aD,s0);
      float4 bA=a1p[4*c+0], bB=a1p[4*c+1], bC=a1p[4*c+2], bD=a1p[4*c+3];
      s1 = sc4f(wA,kA,bA,s1); s1 = sc4f(wB,kB,bB,s1);
      s1 = sc4f(wC,kC,bC,s1); s1 = sc4f(wD,kD,bD,s1);
    }
    part[H][0][u] = s0; part[H][1][u] = s1;
  }
  __syncthreads();

  {
    float sc = batt + sumW - 2.0f * (part[0][H][u] + part[1][H][u]);
    float m = waveRedMax(sc);
    if (lane == 0) redm[H][wq8] = m;
    __syncthreads();
    float bm = fmaxf(fmaxf(fmaxf(redm[H][0],redm[H][1]),fmaxf(redm[H][2],redm[H][3])),
                     fmaxf(fmaxf(redm[H][4],redm[H][5]),fmaxf(redm[H][6],redm[H][7])));
    float e = EXP2F((sc - bm) * L2E);
    float se = waveRedSum(e);
    if (lane == 0) reds[H][wq8] = se;
    __syncthreads();
    float bs = reds[H][0]+reds[H][1]+reds[H][2]+reds[H][3]
             + reds[H][4]+reds[H][5]+reds[H][6]+reds[H][7];
    float pv = e * RCPF(bs);
    pr[H][u] = pv;
    probs[((size_t)(b * TQ + qabs0 + H)) * TK + u] = pv;
  }
  __syncthreads();

  {
    const float* vcol = values + ((size_t)(b * TK) + 256 * H) * NN + u;
    const float4* p0 = (const float4*)(pr[0] + 256 * H);
    const float4* p1 = (const float4*)(pr[1] + 256 * H);
    float c0a=0.f, c0b=0.f, c1a=0.f, c1b=0.f;
    #pragma unroll 2
    for (int k = 0; k < 256; k += 8) {
      float v0 = vcol[(size_t)(k+0)*NN]; float v1 = vcol[(size_t)(k+1)*NN];
      float v2 = vcol[(size_t)(k+2)*NN]; float v3 = vcol[(size_t)(k+3)*NN];
      float v4 = vcol[(size_t)(k+4)*NN]; float v5 = vcol[(size_t)(k+5)*NN];
      float v6 = vcol[(size_t)(k+6)*NN]; float v7 = vcol[(size_t)(k+7)*NN];
      float4 pA = p0[k>>2], pB = p0[(k>>2)+1];
      float4 qA = p1[k>>2], qB = p1[(k>>2)+1];
      c0a = fmaf(pA.x,v0,c0a); c0a = fmaf(pA.y,v1,c0a);
      c0b = fmaf(pA.z,v2,c0b); c0b = fmaf(pA.w,v3,c0b);
      c0a = fmaf(pB.x,v4,c0a); c0a = fmaf(pB.y,v5,c0a);
      c0b = fmaf(pB.z,v6,c0b); c0b = fmaf(pB.w,v7,c0b);
      c1a = fmaf(qA.x,v0,c1a); c1a = fmaf(qA.y,v1,c1a);
      c1b = fmaf(qA.z,v2,c1b); c1b = fmaf(qA.w,v3,c1b);
      c1a = fmaf(qB.x,v4,c1a); c1a = fmaf(qB.y,v5,c1a);
      c1b = fmaf(qB.z,v6,c1b); c1b = fmaf(qB.w,v7,c1b);
    }
    part[H][0][u] = c0a + c0b; part[H][1][u] = c1a + c1b;
  }
  __syncthreads();
  ctx[H][u] = part[0][H][u] + part[1][H][u];
  __syncthreads();

  {
    const float4* wo = (const float4*)(W_out + (size_t)u * CATSZ + 512 * H);
    const float4* x4 = (H == 0) ? (const float4*)qv[0] : (const float4*)ctx[0];
    const float4* y4 = (H == 0) ? (const float4*)qv[1] : (const float4*)ctx[1];
    float o0=0.f, o0b=0.f, o1=0.f, o1b=0.f;
    #pragma unroll 2
    for (int c = 0; c < 32; ++c) {
      float4 wA=wo[4*c+0], wB=wo[4*c+1], wC=wo[4*c+2], wD=wo[4*c+3];
      float4 xA=x4[4*c+0], xB=x4[4*c+1], xC=x4[4*c+2], xD=x4[4*c+3];
      o0 = fma4(wA,xA,o0); o0b = fma4(wB,xB,o0b);
      o0 = fma4(wC,xC,o0); o0b = fma4(wD,xD,o0b);
      float4 yA=y4[4*c+0], yB=y4[4*c+1], yC=y4[4*c+2], yD=y4[4*c+3];
      o1 = fma4(wA,yA,o1); o1b = fma4(wB,yB,o1b);
      o1 = fma4(wC,yC,o1); o1b = fma4(wD,yD,o1b);
    }
    part[H][0][u] = o0 + o0b; part[H][1][u] = o1 + o1b;
  }
  __syncthreads();
  {
    float oo = part[0][H][u] + part[1][H][u] + b_out[u];
    out[((size_t)(b * TQ + qabs0 + H)) * OUTSZ + u] = fast_tanh(oo);
  }
}

extern "C" void kernel_launch(void* const* d_in, const int* in_sizes, int n_in,
                              void* d_out, int out_size, void* d_ws, size_t ws_size,
                              hipStream_t stream) {
  const float* query = (const float*)d_in[0];
  const float* keys  = (const float*)d_in[1];
  const float* vals  = (const float*)d_in[2];
  const float* W_q   = (const float*)d_in[3];
  const float* b_q   = (const float*)d_in[4];
  const float* w_att = (const float*)d_in[5];
  const float* b_att = (const float*)d_in[6];
  const float* W_out = (const float*)d_in[7];
  const float* b_out = (const float*)d_in[8];

  float* out   = (float*)d_out;
  float* probs = out + (size_t)BB * TQ * OUTSZ;

  if (ws_size >= (size_t)WS_FLOATS * sizeof(float)) {
    float* ws = (float*)d_ws;
    pack_kernel<<<dim3(1792), dim3(256), 0, stream>>>(keys, W_q, W_out, ws);
    attn_main<<<dim3(BB * TQ / 2), dim3(1024), 0, stream>>>(
        query, vals, b_q, w_att, b_att, b_out, ws, out, probs);
  } else {
    attn_fallback<<<dim3(BB * TQ / 2), dim3(1024), 0, stream>>>(
        query, keys, vals, W_q, b_q, w_att, b_att, W_out, b_out, out, probs);
  }
}

// Round 8
// 132.747 us; speedup vs baseline: 7.9021x; 1.1750x over previous
//
#include <hip/hip_runtime.h>

// Shape: b=4, t_q=128, t_k=512, n=512, out=512. All fp32.
// Output: [out (4*128*512), probs (4*128*512)].
//
// Round-8: round-7 was LDS-BW-bound (per-CU ds pipe, every iter of every
// thread did a broadcast read: ~65us of LDS serialization). Fixes:
//  (a) thread owns a QUAD of outputs (k4/n4/o4) -> one LDS broadcast feeds
//      8 fma chains (4 outputs x 2 q rows): LDS demand /4.
//  (b) exp factoring: exp(2(aq+k)) = A[n,q]*E[n,k]; E=exp2(K2E*keys)
//      precomputed in pack kernel, A computed once per (n,q). Score inner
//      op = fma(E,A,1) -> rcp -> fma: 1 trans (was 2), 3 VALU (was ~5).
// Contraction split 8 ways (G=t>>7); partials combine via 32KB LDS scratch.

#define BB    4
#define TQ    128
#define TK    512
#define NN    512
#define OUTSZ 512
#define CATSZ 1024
#define K2E   2.8853900817779268f   // 2*log2(e)
#define L2E   1.4426950408889634f   // log2(e)
#define MAT   262144                // 512*512 floats
#define WS_FLOATS (7 * MAT)         // keysE(4) + W_qT(1) + W_outT(2)

#if __has_builtin(__builtin_amdgcn_exp2f)
#define EXP2F(x) __builtin_amdgcn_exp2f(x)
#else
#define EXP2F(x) exp2f(x)
#endif
#if __has_builtin(__builtin_amdgcn_rcpf)
#define RCPF(x) __builtin_amdgcn_rcpf(x)
#else
#define RCPF(x) (1.0f / (x))
#endif

__device__ __forceinline__ float fast_tanh(float x) {
  float e = EXP2F(x * K2E);
  return fmaf(-2.0f, RCPF(e + 1.0f), 1.0f);
}
__device__ __forceinline__ float waveRedSum(float s) {
  #pragma unroll
  for (int m = 32; m >= 1; m >>= 1) s += __shfl_xor(s, m, 64);
  return s;
}
__device__ __forceinline__ float waveRedMax(float s) {
  #pragma unroll
  for (int m = 32; m >= 1; m >>= 1) s = fmaxf(s, __shfl_xor(s, m, 64));
  return s;
}
__device__ __forceinline__ float fma4(float4 w, float4 v, float acc) {
  acc = fmaf(w.x, v.x, acc); acc = fmaf(w.y, v.y, acc);
  acc = fmaf(w.z, v.z, acc); acc = fmaf(w.w, v.w, acc);
  return acc;
}
// acc[quad] += w[quad] * s
__device__ __forceinline__ float4 fma4s(float4 a, float4 w, float s) {
  a.x = fmaf(w.x, s, a.x); a.y = fmaf(w.y, s, a.y);
  a.z = fmaf(w.z, s, a.z); a.w = fmaf(w.w, s, a.w);
  return a;
}
// score quad: s[i] += w * rcp(E[i]*A + 1)
__device__ __forceinline__ float4 scq(float4 s, float4 E, float A, float w) {
  s.x = fmaf(w, RCPF(fmaf(E.x, A, 1.0f)), s.x);
  s.y = fmaf(w, RCPF(fmaf(E.y, A, 1.0f)), s.y);
  s.z = fmaf(w, RCPF(fmaf(E.z, A, 1.0f)), s.z);
  s.w = fmaf(w, RCPF(fmaf(E.w, A, 1.0f)), s.w);
  return s;
}

// ---------------- pack kernel ------------------------------------------------
// ws layout (floats): [0,4*MAT) keysE[b][n][k] = exp2(K2E*keys[b][k][n]);
//                     [4*MAT,5*MAT) W_qT[d][n]; [5*MAT,7*MAT) W_outT[c][o].
__global__ __launch_bounds__(256)
void pack_kernel(const float* __restrict__ keys, const float* __restrict__ W_q,
                 const float* __restrict__ W_out, float* __restrict__ ws)
{
  __shared__ float tile[32][33];
  const int idx = blockIdx.x;
  const float* src; float* dst; int M, N; float scale; int by, bx; bool doExp;
  if (idx < 1024) {                       // keys: 4 x (512x512), exp2 packed
    int b = idx >> 8, r = idx & 255;
    by = r >> 4; bx = r & 15;
    src = keys + (size_t)b * MAT; dst = ws + (size_t)b * MAT;
    M = 512; N = 512; scale = K2E; doExp = true;
  } else if (idx < 1280) {                // W_q 512x512
    int r = idx - 1024; by = r >> 4; bx = r & 15;
    src = W_q; dst = ws + (size_t)4 * MAT; M = 512; N = 512; scale = 1.0f; doExp = false;
  } else {                                // W_out 512x1024 -> 1024x512
    int r = idx - 1280; by = r >> 5; bx = r & 31;
    src = W_out; dst = ws + (size_t)5 * MAT; M = 512; N = 1024; scale = 1.0f; doExp = false;
  }
  const int tx = threadIdx.x & 31, ty = threadIdx.x >> 5;   // 32x8
  #pragma unroll
  for (int i = 0; i < 32; i += 8)
    tile[ty + i][tx] = src[(size_t)(by * 32 + ty + i) * N + bx * 32 + tx] * scale;
  __syncthreads();
  #pragma unroll
  for (int i = 0; i < 32; i += 8) {
    float v = tile[tx][ty + i];
    dst[(size_t)(bx * 32 + ty + i) * M + by * 32 + tx] = doExp ? EXP2F(v) : v;
  }
}

// ---------------- main kernel ------------------------------------------------
__global__ __launch_bounds__(1024, 4)
void attn_main(const float* __restrict__ query, const float* __restrict__ values,
               const float* __restrict__ b_q, const float* __restrict__ w_att,
               const float* __restrict__ b_att, const float* __restrict__ b_out,
               const float* __restrict__ ws,
               float* __restrict__ out, float* __restrict__ probs)
{
  __shared__ __align__(16) float2 catI[CATSZ];   // {row0,row1}: [0,512) query, [512,1024) ctx
  __shared__ __align__(16) float4 paw[NN];       // {A0, A1, w, pad}
  __shared__ __align__(16) float2 prI[TK];       // {p0[k], p1[k]}
  __shared__ __align__(16) float  pt[8][2][NN];  // [G][q][idx] partial scratch
  __shared__ float redm[2][8], reds2[2][8], redw[8];

  const float* wsKeys = ws;
  const float* wsWq   = ws + (size_t)4 * MAT;
  const float* wsWout = ws + (size_t)5 * MAT;

  const int t    = threadIdx.x;        // 0..1023
  const int qh   = t >> 9;             // combine-phase q row (0/1)
  const int u    = t & 511;            // combine-phase index
  const int G    = t >> 7;             // contraction range 0..7 (wave-uniform)
  const int v    = t & 127;            // output quad index (4v..4v+3)
  const int wave = t >> 6, lane = t & 63, wq8 = wave & 7;

  const int p  = blockIdx.x;                 // 0..255 (XCD swizzle)
  const int b  = (p & 7) >> 1;
  const int qg = ((p >> 3) << 1) | (p & 1);
  const int qabs0 = qg * 2;

  const float batt = b_att[0];

  // ---- stage: query rows -> catI[0:512), w_att partial sum ----
  float w_own = 0.f;
  if (qh == 0) {
    float q0 = query[((size_t)(b * TQ + qabs0 + 0)) * NN + u];
    float q1 = query[((size_t)(b * TQ + qabs0 + 1)) * NN + u];
    catI[u] = make_float2(q0, q1);
  } else {
    w_own = w_att[u];
  }
  if (qh == 1) {
    float wp = waveRedSum(w_own);
    if (lane == 0) redw[wq8] = wp;
  }
  __syncthreads();
  const float sumW = redw[0]+redw[1]+redw[2]+redw[3]+redw[4]+redw[5]+redw[6]+redw[7];

  // ---- step 1: att_q partials.  Thread (G,v): n quad 4v.., d in [64G,+64).
  {
    const float* wq = wsWq + 4 * v;
    float4 a0 = {0,0,0,0}, a1 = {0,0,0,0};
    #pragma unroll 2
    for (int j = 0; j < 64; j += 2) {
      int d = 64 * G + j;
      float4 wA = *(const float4*)(wq + (size_t)d * 512);
      float4 wB = *(const float4*)(wq + (size_t)(d + 1) * 512);
      float4 qq = *(const float4*)(&catI[d]);   // {q0[d],q1[d],q0[d+1],q1[d+1]}
      a0 = fma4s(a0, wA, qq.x); a1 = fma4s(a1, wA, qq.y);
      a0 = fma4s(a0, wB, qq.z); a1 = fma4s(a1, wB, qq.w);
    }
    *(float4*)(&pt[G][0][4 * v]) = a0;
    *(float4*)(&pt[G][1][4 * v]) = a1;
  }
  __syncthreads();
  // combine: thread (qh,u): A = exp2(K2E * att_q); build paw
  {
    float s = pt[0][qh][u] + pt[1][qh][u] + pt[2][qh][u] + pt[3][qh][u]
            + pt[4][qh][u] + pt[5][qh][u] + pt[6][qh][u] + pt[7][qh][u];
    float A = EXP2F(K2E * (s + b_q[u]));
    if (qh == 0) { paw[u].x = A; paw[u].z = w_att[u]; }
    else         { paw[u].y = A; }
  }
  __syncthreads();

  // ---- step 2 (hot): score partials.  Thread (G,v): k quad 4v.., n in [64G,+64).
  //      score_q[k] = batt + sumW - 2 * sum_n w[n] * rcp(E[n][k]*A[n][q] + 1)
  {
    const float* ke = wsKeys + (size_t)b * MAT + 4 * v;
    float4 s0 = {0,0,0,0}, s1 = {0,0,0,0};
    #pragma unroll 4
    for (int j = 0; j < 64; ++j) {
      int n = 64 * G + j;
      float4 E  = *(const float4*)(ke + (size_t)n * 512);
      float4 pw = paw[n];
      s0 = scq(s0, E, pw.x, pw.z);
      s1 = scq(s1, E, pw.y, pw.z);
    }
    *(float4*)(&pt[G][0][4 * v]) = s0;
    *(float4*)(&pt[G][1][4 * v]) = s1;
  }
  __syncthreads();

  // ---- softmax: thread (qh,u) owns q=qh, k=u.
  {
    float s = pt[0][qh][u] + pt[1][qh][u] + pt[2][qh][u] + pt[3][qh][u]
            + pt[4][qh][u] + pt[5][qh][u] + pt[6][qh][u] + pt[7][qh][u];
    float sc = batt + sumW - 2.0f * s;
    float m = waveRedMax(sc);
    if (lane == 0) redm[qh][wq8] = m;
    __syncthreads();
    float bm = fmaxf(fmaxf(fmaxf(redm[qh][0],redm[qh][1]),fmaxf(redm[qh][2],redm[qh][3])),
                     fmaxf(fmaxf(redm[qh][4],redm[qh][5]),fmaxf(redm[qh][6],redm[qh][7])));
    float e = EXP2F((sc - bm) * L2E);
    float se = waveRedSum(e);
    if (lane == 0) reds2[qh][wq8] = se;
    __syncthreads();
    float bs = reds2[qh][0]+reds2[qh][1]+reds2[qh][2]+reds2[qh][3]
             + reds2[qh][4]+reds2[qh][5]+reds2[qh][6]+reds2[qh][7];
    float pv = e * RCPF(bs);
    if (qh == 0) prI[u].x = pv; else prI[u].y = pv;
    probs[((size_t)(b * TQ + qabs0 + qh)) * TK + u] = pv;
  }
  __syncthreads();

  // ---- step 4: context partials.  Thread (G,v): n quad 4v.., k in [64G,+64).
  {
    const float* vv = values + ((size_t)(b * TK + 64 * G)) * NN + 4 * v;
    float4 c0 = {0,0,0,0}, c1 = {0,0,0,0};
    #pragma unroll 2
    for (int j = 0; j < 64; j += 2) {
      float4 vA = *(const float4*)(vv + (size_t)j * NN);
      float4 vB = *(const float4*)(vv + (size_t)(j + 1) * NN);
      float4 pp = *(const float4*)(&prI[64 * G + j]); // {p0[k],p1[k],p0[k+1],p1[k+1]}
      c0 = fma4s(c0, vA, pp.x); c1 = fma4s(c1, vA, pp.y);
      c0 = fma4s(c0, vB, pp.z); c1 = fma4s(c1, vB, pp.w);
    }
    *(float4*)(&pt[G][0][4 * v]) = c0;
    *(float4*)(&pt[G][1][4 * v]) = c1;
  }
  __syncthreads();
  {
    float s = pt[0][qh][u] + pt[1][qh][u] + pt[2][qh][u] + pt[3][qh][u]
            + pt[4][qh][u] + pt[5][qh][u] + pt[6][qh][u] + pt[7][qh][u];
    if (qh == 0) catI[512 + u].x = s; else catI[512 + u].y = s;
  }
  __syncthreads();

  // ---- step 5: out partials.  Thread (G,v): o quad 4v.., c in [128G,+128).
  {
    const float* wo = wsWout + 4 * v;
    float4 o0 = {0,0,0,0}, o1 = {0,0,0,0};
    #pragma unroll 2
    for (int j = 0; j < 128; j += 2) {
      int c = 128 * G + j;
      float4 wA = *(const float4*)(wo + (size_t)c * 512);
      float4 wB = *(const float4*)(wo + (size_t)(c + 1) * 512);
      float4 cc = *(const float4*)(&catI[c]);   // {cat0[c],cat1[c],cat0[c+1],cat1[c+1]}
      o0 = fma4s(o0, wA, cc.x); o1 = fma4s(o1, wA, cc.y);
      o0 = fma4s(o0, wB, cc.z); o1 = fma4s(o1, wB, cc.w);
    }
    *(float4*)(&pt[G][0][4 * v]) = o0;
    *(float4*)(&pt[G][1][4 * v]) = o1;
  }
  __syncthreads();
  {
    float s = pt[0][qh][u] + pt[1][qh][u] + pt[2][qh][u] + pt[3][qh][u]
            + pt[4][qh][u] + pt[5][qh][u] + pt[6][qh][u] + pt[7][qh][u];
    float oo = s + b_out[u];
    out[((size_t)(b * TQ + qabs0 + qh)) * OUTSZ + u] = fast_tanh(oo);
  }
}

// ---------------- round-6-style fallback (ws too small) ----------------------
__device__ __forceinline__ float sc4f(float4 w, float4 k, float4 a, float acc) {
  acc = fmaf(w.x, RCPF(EXP2F(fmaf(k.x, K2E, a.x)) + 1.0f), acc);
  acc = fmaf(w.y, RCPF(EXP2F(fmaf(k.y, K2E, a.y)) + 1.0f), acc);
  acc = fmaf(w.z, RCPF(EXP2F(fmaf(k.z, K2E, a.z)) + 1.0f), acc);
  acc = fmaf(w.w, RCPF(EXP2F(fmaf(k.w, K2E, a.w)) + 1.0f), acc);
  return acc;
}

__global__ __launch_bounds__(1024, 4)
void attn_fallback(const float* __restrict__ query, const float* __restrict__ keys,
                   const float* __restrict__ values, const float* __restrict__ W_q,
                   const float* __restrict__ b_q, const float* __restrict__ w_att,
                   const float* __restrict__ b_att, const float* __restrict__ W_out,
                   const float* __restrict__ b_out,
                   float* __restrict__ out, float* __restrict__ probs)
{
  __shared__ __align__(16) float qv[2][NN];
  __shared__ __align__(16) float aqc[2][NN];
  __shared__ __align__(16) float wv[NN];
  __shared__ __align__(16) float pr[2][TK];
  __shared__ __align__(16) float ctx[2][NN];
  __shared__ __align__(16) float part[2][2][NN];
  __shared__ float redm[2][8], reds[2][8], redw[8];

  const int t = threadIdx.x, H = t >> 9, u = t & 511;
  const int wave = t >> 6, lane = t & 63, wq8 = wave & 7;
  const int p = blockIdx.x, b = (p & 7) >> 1;
  const int qg = ((p >> 3) << 1) | (p & 1), qabs0 = qg * 2;
  const float batt = b_att[0];

  if (H == 0) wv[u] = w_att[u];
  qv[H][u] = query[((size_t)(b * TQ + qabs0 + H)) * NN + u];
  __syncthreads();
  if (H == 0) {
    float wp = waveRedSum(wv[u]);
    if (lane == 0) redw[wq8] = wp;
  }
  __syncthreads();
  const float sumW = redw[0]+redw[1]+redw[2]+redw[3]+redw[4]+redw[5]+redw[6]+redw[7];

  {
    const float4* wq4 = (const float4*)(W_q + (size_t)u * NN + 256 * H);
    const float4* x4  = (const float4*)(qv[0] + 256 * H);
    const float4* y4  = (const float4*)(qv[1] + 256 * H);
    float a0=0.f, a0b=0.f, a1=0.f, a1b=0.f;
    #pragma unroll 2
    for (int c = 0; c < 16; ++c) {
      float4 wA=wq4[4*c+0], wB=wq4[4*c+1], wC=wq4[4*c+2], wD=wq4[4*c+3];
      float4 xA=x4[4*c+0], xB=x4[4*c+1], xC=x4[4*c+2], xD=x4[4*c+3];
      a0 = fma4(wA,xA,a0); a0b = fma4(wB,xB,a0b);
      a0 = fma4(wC,xC,a0); a0b = fma4(wD,xD,a0b);
      float4 yA=y4[4*c+0], yB=y4[4*c+1], yC=y4[4*c+2], yD=y4[4*c+3];
      a1 = fma4(wA,yA,a1); a1b = fma4(wB,yB,a1b);
      a1 = fma4(wC,yC,a1); a1b = fma4(wD,yD,a1b);
    }
    part[H][0][u] = a0 + a0b; part[H][1][u] = a1 + a1b;
  }
  __syncthreads();
  aqc[H][u] = (part[0][H][u] + part[1][H][u] + b_q[u]) * K2E;
  __syncthreads();

  {
    const float4* kr  = (const float4*)(keys + ((size_t)(b * TK) + u) * NN + 256 * H);
    const float4* a0p = (const float4*)(aqc[0] + 256 * H);
    const float4* a1p = (const float4*)(aqc[1] + 256 * H);
    const float4* w4  = (const float4*)(wv + 256 * H);
    float s0 = 0.f, s1 = 0.f;
    #pragma unroll 2
    for (int c = 0; c < 16; ++c) {
      float4 kA=kr[4*c+0], kB=kr[4*c+1], kC=kr[4*c+2], kD=kr[4*c+3];
      float4 wA=w4[4*c+0], wB=w4[4*c+1], wC=w4[4*c+2], wD=w4[4*c+3];
      float4 aA=a0p[4*c+0], aB=a0p[4*c+1], aC=a0p[4*c+2], aD=a0p[4*c+3];
      s0 = sc4f(wA,kA,aA,s0); s0 = sc4f(wB,kB,aB,s0);
      s0 = sc4f(wC,kC,aC,s0); s0 = sc4f(wD,kD,aD,s0);
      float4 bA=a1p[4*c+0], bB=a1p[4*c+1], bC=a1p[4*c+2], bD=a1p[4*c+3];
      s1 = sc4f(wA,kA,bA,s1); s1 = sc4f(wB,kB,bB,s1);
      s1 = sc4f(wC,kC,bC,s1); s1 = sc4f(wD,kD,bD,s1);
    }
    part[H][0][u] = s0; part[H][1][u] = s1;
  }
  __syncthreads();

  {
    float sc = batt + sumW - 2.0f * (part[0][H][u] + part[1][H][u]);
    float m = waveRedMax(sc);
    if (lane == 0) redm[H][wq8] = m;
    __syncthreads();
    float bm = fmaxf(fmaxf(fmaxf(redm[H][0],redm[H][1]),fmaxf(redm[H][2],redm[H][3])),
                     fmaxf(fmaxf(redm[H][4],redm[H][5]),fmaxf(redm[H][6],redm[H][7])));
    float e = EXP2F((sc - bm) * L2E);
    float se = waveRedSum(e);
    if (lane == 0) reds[H][wq8] = se;
    __syncthreads();
    float bs = reds[H][0]+reds[H][1]+reds[H][2]+reds[H][3]
             + reds[H][4]+reds[H][5]+reds[H][6]+reds[H][7];
    float pv = e * RCPF(bs);
    pr[H][u] = pv;
    probs[((size_t)(b * TQ + qabs0 + H)) * TK + u] = pv;
  }
  __syncthreads();

  {
    const float* vcol = values + ((size_t)(b * TK) + 256 * H) * NN + u;
    const float4* p0 = (const float4*)(pr[0] + 256 * H);
    const float4* p1 = (const float4*)(pr[1] + 256 * H);
    float c0a=0.f, c0b=0.f, c1a=0.f, c1b=0.f;
    #pragma unroll 2
    for (int k = 0; k < 256; k += 8) {
      float v0 = vcol[(size_t)(k+0)*NN]; float v1 = vcol[(size_t)(k+1)*NN];
      float v2 = vcol[(size_t)(k+2)*NN]; float v3 = vcol[(size_t)(k+3)*NN];
      float v4 = vcol[(size_t)(k+4)*NN]; float v5 = vcol[(size_t)(k+5)*NN];
      float v6 = vcol[(size_t)(k+6)*NN]; float v7 = vcol[(size_t)(k+7)*NN];
      float4 pA = p0[k>>2], pB = p0[(k>>2)+1];
      float4 qA = p1[k>>2], qB = p1[(k>>2)+1];
      c0a = fmaf(pA.x,v0,c0a); c0a = fmaf(pA.y,v1,c0a);
      c0b = fmaf(pA.z,v2,c0b); c0b = fmaf(pA.w,v3,c0b);
      c0a = fmaf(pB.x,v4,c0a); c0a = fmaf(pB.y,v5,c0a);
      c0b = fmaf(pB.z,v6,c0b); c0b = fmaf(pB.w,v7,c0b);
      c1a = fmaf(qA.x,v0,c1a); c1a = fmaf(qA.y,v1,c1a);
      c1b = fmaf(qA.z,v2,c1b); c1b = fmaf(qA.w,v3,c1b);
      c1a = fmaf(qB.x,v4,c1a); c1a = fmaf(qB.y,v5,c1a);
      c1b = fmaf(qB.z,v6,c1b); c1b = fmaf(qB.w,v7,c1b);
    }
    part[H][0][u] = c0a + c0b; part[H][1][u] = c1a + c1b;
  }
  __syncthreads();
  ctx[H][u] = part[0][H][u] + part[1][H][u];
  __syncthreads();

  {
    const float4* wo = (const float4*)(W_out + (size_t)u * CATSZ + 512 * H);
    const float4* x4 = (H == 0) ? (const float4*)qv[0] : (const float4*)ctx[0];
    const float4* y4 = (H == 0) ? (const float4*)qv[1] : (const float4*)ctx[1];
    float o0=0.f, o0b=0.f, o1=0.f, o1b=0.f;
    #pragma unroll 2
    for (int c = 0; c < 32; ++c) {
      float4 wA=wo[4*c+0], wB=wo[4*c+1], wC=wo[4*c+2], wD=wo[4*c+3];
      float4 xA=x4[4*c+0], xB=x4[4*c+1], xC=x4[4*c+2], xD=x4[4*c+3];
      o0 = fma4(wA,xA,o0); o0b = fma4(wB,xB,o0b);
      o0 = fma4(wC,xC,o0); o0b = fma4(wD,xD,o0b);
      float4 yA=y4[4*c+0], yB=y4[4*c+1], yC=y4[4*c+2], yD=y4[4*c+3];
      o1 = fma4(wA,yA,o1); o1b = fma4(wB,yB,o1b);
      o1 = fma4(wC,yC,o1); o1b = fma4(wD,yD,o1b);
    }
    part[H][0][u] = o0 + o0b; part[H][1][u] = o1 + o1b;
  }
  __syncthreads();
  {
    float oo = part[0][H][u] + part[1][H][u] + b_out[u];
    out[((size_t)(b * TQ + qabs0 + H)) * OUTSZ + u] = fast_tanh(oo);
  }
}

extern "C" void kernel_launch(void* const* d_in, const int* in_sizes, int n_in,
                              void* d_out, int out_size, void* d_ws, size_t ws_size,
                              hipStream_t stream) {
  const float* query = (const float*)d_in[0];
  const float* keys  = (const float*)d_in[1];
  const float* vals  = (const float*)d_in[2];
  const float* W_q   = (const float*)d_in[3];
  const float* b_q   = (const float*)d_in[4];
  const float* w_att = (const float*)d_in[5];
  const float* b_att = (const float*)d_in[6];
  const float* W_out = (const float*)d_in[7];
  const float* b_out = (const float*)d_in[8];

  float* out   = (float*)d_out;
  float* probs = out + (size_t)BB * TQ * OUTSZ;

  if (ws_size >= (size_t)WS_FLOATS * sizeof(float)) {
    float* ws = (float*)d_ws;
    pack_kernel<<<dim3(1792), dim3(256), 0, stream>>>(keys, W_q, W_out, ws);
    attn_main<<<dim3(BB * TQ / 2), dim3(1024), 0, stream>>>(
        query, vals, b_q, w_att, b_att, b_out, ws, out, probs);
  } else {
    attn_fallback<<<dim3(BB * TQ / 2), dim3(1024), 0, stream>>>(
        query, keys, vals, W_q, b_q, w_att, b_att, W_out, b_out, out, probs);
  }
}

// Round 9
// 130.246 us; speedup vs baseline: 8.0538x; 1.0192x over previous
//
#include <hip/hip_runtime.h>

// Shape: b=4, t_q=128, t_k=512, n=512, out=512. All fp32 in/out.
// Output: [out (4*128*512), probs (4*128*512)].
//
// Round-9: round-8 was L2-BW-bound (1.28 GB L2->CU per launch; per-XCD
// working set 5MB > 4MB L2). Fix: all streamed operands packed to fp16
// (keysE=exp2(K2E*keys) transposed, W_qT, W_outT transposed, values
// converted in layout). Bytes halve (640MB), per-XCD set 2.5MB fits L2.
// Inner loops use fmaf((float)h,...) -> v_fma_mix_f32 (no cvt cost).
// Structure otherwise round-8: 1024 thr, quad-of-outputs per thread,
// 8-way contraction split, exp-factored score (1 trans/elem).

#include <hip/hip_fp16.h>

#define BB    4
#define TQ    128
#define TK    512
#define NN    512
#define OUTSZ 512
#define CATSZ 1024
#define K2E   2.8853900817779268f   // 2*log2(e)
#define L2E   1.4426950408889634f   // log2(e)
#define MAT   262144                // 512*512
// ws layout in halves: keysE[0,4M) W_qT[4M,5M) W_outT[5M,7M) values[7M,11M)
#define WS_HALVES (11 * MAT)

typedef __attribute__((ext_vector_type(4))) _Float16 half4;

#if __has_builtin(__builtin_amdgcn_exp2f)
#define EXP2F(x) __builtin_amdgcn_exp2f(x)
#else
#define EXP2F(x) exp2f(x)
#endif
#if __has_builtin(__builtin_amdgcn_rcpf)
#define RCPF(x) __builtin_amdgcn_rcpf(x)
#else
#define RCPF(x) (1.0f / (x))
#endif

__device__ __forceinline__ float fast_tanh(float x) {
  float e = EXP2F(x * K2E);
  return fmaf(-2.0f, RCPF(e + 1.0f), 1.0f);
}
__device__ __forceinline__ float waveRedSum(float s) {
  #pragma unroll
  for (int m = 32; m >= 1; m >>= 1) s += __shfl_xor(s, m, 64);
  return s;
}
__device__ __forceinline__ float waveRedMax(float s) {
  #pragma unroll
  for (int m = 32; m >= 1; m >>= 1) s = fmaxf(s, __shfl_xor(s, m, 64));
  return s;
}
__device__ __forceinline__ float fma4(float4 w, float4 v, float acc) {
  acc = fmaf(w.x, v.x, acc); acc = fmaf(w.y, v.y, acc);
  acc = fmaf(w.z, v.z, acc); acc = fmaf(w.w, v.w, acc);
  return acc;
}
// acc[quad] += w_h[quad] * s   (fp16 source -> v_fma_mix)
__device__ __forceinline__ float4 fma4sh(float4 a, half4 w, float s) {
  a.x = fmaf((float)w.x, s, a.x); a.y = fmaf((float)w.y, s, a.y);
  a.z = fmaf((float)w.z, s, a.z); a.w = fmaf((float)w.w, s, a.w);
  return a;
}
// score quad: s[i] += w * rcp(E_h[i]*A + 1)
__device__ __forceinline__ float4 scqh(float4 s, half4 E, float A, float w) {
  s.x = fmaf(w, RCPF(fmaf((float)E.x, A, 1.0f)), s.x);
  s.y = fmaf(w, RCPF(fmaf((float)E.y, A, 1.0f)), s.y);
  s.z = fmaf(w, RCPF(fmaf((float)E.z, A, 1.0f)), s.z);
  s.w = fmaf(w, RCPF(fmaf((float)E.w, A, 1.0f)), s.w);
  return s;
}

// ---------------- pack kernel ------------------------------------------------
__global__ __launch_bounds__(256)
void pack_kernel(const float* __restrict__ keys, const float* __restrict__ W_q,
                 const float* __restrict__ W_out, const float* __restrict__ values,
                 _Float16* __restrict__ ws)
{
  __shared__ float tile[32][33];
  const int idx = blockIdx.x;
  if (idx >= 1792) {                      // values: elementwise cvt, 512 blocks
    int r = idx - 1792;                   // 0..511, 2048 elems each
    size_t off = (size_t)r * 2048 + threadIdx.x * 8;
    float4 a = *(const float4*)(values + off);
    float4 b = *(const float4*)(values + off + 4);
    _Float16* dst = ws + (size_t)7 * MAT + off;
    half4 h0 = {(_Float16)a.x, (_Float16)a.y, (_Float16)a.z, (_Float16)a.w};
    half4 h1 = {(_Float16)b.x, (_Float16)b.y, (_Float16)b.z, (_Float16)b.w};
    *(half4*)(dst) = h0;
    *(half4*)(dst + 4) = h1;
    return;
  }
  const float* src; _Float16* dst; int M, N; float scale; int by, bx; bool doExp;
  if (idx < 1024) {                       // keys: 4 x (512x512), exp2, transpose
    int b = idx >> 8, r = idx & 255;
    by = r >> 4; bx = r & 15;
    src = keys + (size_t)b * MAT; dst = ws + (size_t)b * MAT;
    M = 512; N = 512; scale = K2E; doExp = true;
  } else if (idx < 1280) {                // W_q 512x512 transpose
    int r = idx - 1024; by = r >> 4; bx = r & 15;
    src = W_q; dst = ws + (size_t)4 * MAT; M = 512; N = 512; scale = 1.0f; doExp = false;
  } else {                                // W_out 512x1024 -> 1024x512 transpose
    int r = idx - 1280; by = r >> 5; bx = r & 31;
    src = W_out; dst = ws + (size_t)5 * MAT; M = 512; N = 1024; scale = 1.0f; doExp = false;
  }
  const int tx = threadIdx.x & 31, ty = threadIdx.x >> 5;   // 32x8
  #pragma unroll
  for (int i = 0; i < 32; i += 8)
    tile[ty + i][tx] = src[(size_t)(by * 32 + ty + i) * N + bx * 32 + tx] * scale;
  __syncthreads();
  #pragma unroll
  for (int i = 0; i < 32; i += 8) {
    float v = tile[tx][ty + i];
    if (doExp) v = EXP2F(v);
    dst[(size_t)(bx * 32 + ty + i) * M + by * 32 + tx] = (_Float16)v;
  }
}

// ---------------- main kernel ------------------------------------------------
__global__ __launch_bounds__(1024, 4)
void attn_main(const float* __restrict__ query,
               const float* __restrict__ b_q, const float* __restrict__ w_att,
               const float* __restrict__ b_att, const float* __restrict__ b_out,
               const _Float16* __restrict__ ws,
               float* __restrict__ out, float* __restrict__ probs)
{
  __shared__ __align__(16) float2 catI[CATSZ];   // {row0,row1}: [0,512) query, [512,1024) ctx
  __shared__ __align__(16) float4 paw[NN];       // {A0, A1, w, pad}
  __shared__ __align__(16) float2 prI[TK];       // {p0[k], p1[k]}
  __shared__ __align__(16) float  pt[8][2][NN];  // [G][q][idx] partial scratch
  __shared__ float redm[2][8], reds2[2][8], redw[8];

  const _Float16* wsKeys = ws;
  const _Float16* wsWq   = ws + (size_t)4 * MAT;
  const _Float16* wsWout = ws + (size_t)5 * MAT;
  const _Float16* wsVal  = ws + (size_t)7 * MAT;

  const int t    = threadIdx.x;        // 0..1023
  const int qh   = t >> 9;             // combine-phase q row (0/1)
  const int u    = t & 511;            // combine-phase index
  const int G    = t >> 7;             // contraction range 0..7 (wave-uniform)
  const int v    = t & 127;            // output quad index (4v..4v+3)
  const int wave = t >> 6, lane = t & 63, wq8 = wave & 7;

  const int p  = blockIdx.x;                 // 0..255 (XCD swizzle)
  const int b  = (p & 7) >> 1;
  const int qg = ((p >> 3) << 1) | (p & 1);
  const int qabs0 = qg * 2;

  const float batt = b_att[0];

  // ---- stage: query rows -> catI[0:512), w_att partial sum ----
  float w_own = 0.f;
  if (qh == 0) {
    float q0 = query[((size_t)(b * TQ + qabs0 + 0)) * NN + u];
    float q1 = query[((size_t)(b * TQ + qabs0 + 1)) * NN + u];
    catI[u] = make_float2(q0, q1);
  } else {
    w_own = w_att[u];
  }
  if (qh == 1) {
    float wp = waveRedSum(w_own);
    if (lane == 0) redw[wq8] = wp;
  }
  __syncthreads();
  const float sumW = redw[0]+redw[1]+redw[2]+redw[3]+redw[4]+redw[5]+redw[6]+redw[7];

  // ---- step 1: att_q partials.  Thread (G,v): n quad 4v.., d in [64G,+64).
  {
    const _Float16* wq = wsWq + 4 * v;
    float4 a0 = {0,0,0,0}, a1 = {0,0,0,0};
    #pragma unroll 4
    for (int j = 0; j < 64; j += 2) {
      int d = 64 * G + j;
      half4 wA = *(const half4*)(wq + (size_t)d * 512);
      half4 wB = *(const half4*)(wq + (size_t)(d + 1) * 512);
      float4 qq = *(const float4*)(&catI[d]);   // {q0[d],q1[d],q0[d+1],q1[d+1]}
      a0 = fma4sh(a0, wA, qq.x); a1 = fma4sh(a1, wA, qq.y);
      a0 = fma4sh(a0, wB, qq.z); a1 = fma4sh(a1, wB, qq.w);
    }
    *(float4*)(&pt[G][0][4 * v]) = a0;
    *(float4*)(&pt[G][1][4 * v]) = a1;
  }
  __syncthreads();
  // combine: thread (qh,u): A = exp2(K2E * att_q); build paw
  {
    float s = pt[0][qh][u] + pt[1][qh][u] + pt[2][qh][u] + pt[3][qh][u]
            + pt[4][qh][u] + pt[5][qh][u] + pt[6][qh][u] + pt[7][qh][u];
    float A = EXP2F(K2E * (s + b_q[u]));
    if (qh == 0) { paw[u].x = A; paw[u].z = w_att[u]; }
    else         { paw[u].y = A; }
  }
  __syncthreads();

  // ---- step 2 (hot): score partials.  Thread (G,v): k quad 4v.., n in [64G,+64).
  {
    const _Float16* ke = wsKeys + (size_t)b * MAT + 4 * v;
    float4 s0 = {0,0,0,0}, s1 = {0,0,0,0};
    #pragma unroll 4
    for (int j = 0; j < 64; ++j) {
      int n = 64 * G + j;
      half4 E   = *(const half4*)(ke + (size_t)n * 512);
      float4 pw = paw[n];
      s0 = scqh(s0, E, pw.x, pw.z);
      s1 = scqh(s1, E, pw.y, pw.z);
    }
    *(float4*)(&pt[G][0][4 * v]) = s0;
    *(float4*)(&pt[G][1][4 * v]) = s1;
  }
  __syncthreads();

  // ---- softmax: thread (qh,u) owns q=qh, k=u.
  {
    float s = pt[0][qh][u] + pt[1][qh][u] + pt[2][qh][u] + pt[3][qh][u]
            + pt[4][qh][u] + pt[5][qh][u] + pt[6][qh][u] + pt[7][qh][u];
    float sc = batt + sumW - 2.0f * s;
    float m = waveRedMax(sc);
    if (lane == 0) redm[qh][wq8] = m;
    __syncthreads();
    float bm = fmaxf(fmaxf(fmaxf(redm[qh][0],redm[qh][1]),fmaxf(redm[qh][2],redm[qh][3])),
                     fmaxf(fmaxf(redm[qh][4],redm[qh][5]),fmaxf(redm[qh][6],redm[qh][7])));
    float e = EXP2F((sc - bm) * L2E);
    float se = waveRedSum(e);
    if (lane == 0) reds2[qh][wq8] = se;
    __syncthreads();
    float bs = reds2[qh][0]+reds2[qh][1]+reds2[qh][2]+reds2[qh][3]
             + reds2[qh][4]+reds2[qh][5]+reds2[qh][6]+reds2[qh][7];
    float pv = e * RCPF(bs);
    if (qh == 0) prI[u].x = pv; else prI[u].y = pv;
    probs[((size_t)(b * TQ + qabs0 + qh)) * TK + u] = pv;
  }
  __syncthreads();

  // ---- step 4: context partials.  Thread (G,v): n quad 4v.., k in [64G,+64).
  {
    const _Float16* vv = wsVal + ((size_t)(b * TK + 64 * G)) * NN + 4 * v;
    float4 c0 = {0,0,0,0}, c1 = {0,0,0,0};
    #pragma unroll 4
    for (int j = 0; j < 64; j += 2) {
      half4 vA = *(const half4*)(vv + (size_t)j * NN);
      half4 vB = *(const half4*)(vv + (size_t)(j + 1) * NN);
      float4 pp = *(const float4*)(&prI[64 * G + j]); // {p0[k],p1[k],p0[k+1],p1[k+1]}
      c0 = fma4sh(c0, vA, pp.x); c1 = fma4sh(c1, vA, pp.y);
      c0 = fma4sh(c0, vB, pp.z); c1 = fma4sh(c1, vB, pp.w);
    }
    *(float4*)(&pt[G][0][4 * v]) = c0;
    *(float4*)(&pt[G][1][4 * v]) = c1;
  }
  __syncthreads();
  {
    float s = pt[0][qh][u] + pt[1][qh][u] + pt[2][qh][u] + pt[3][qh][u]
            + pt[4][qh][u] + pt[5][qh][u] + pt[6][qh][u] + pt[7][qh][u];
    if (qh == 0) catI[512 + u].x = s; else catI[512 + u].y = s;
  }
  __syncthreads();

  // ---- step 5: out partials.  Thread (G,v): o quad 4v.., c in [128G,+128).
  {
    const _Float16* wo = wsWout + 4 * v;
    float4 o0 = {0,0,0,0}, o1 = {0,0,0,0};
    #pragma unroll 4
    for (int j = 0; j < 128; j += 2) {
      int c = 128 * G + j;
      half4 wA = *(const half4*)(wo + (size_t)c * 512);
      half4 wB = *(const half4*)(wo + (size_t)(c + 1) * 512);
      float4 cc = *(const float4*)(&catI[c]);   // {cat0[c],cat1[c],cat0[c+1],cat1[c+1]}
      o0 = fma4sh(o0, wA, cc.x); o1 = fma4sh(o1, wA, cc.y);
      o0 = fma4sh(o0, wB, cc.z); o1 = fma4sh(o1, wB, cc.w);
    }
    *(float4*)(&pt[G][0][4 * v]) = o0;
    *(float4*)(&pt[G][1][4 * v]) = o1;
  }
  __syncthreads();
  {
    float s = pt[0][qh][u] + pt[1][qh][u] + pt[2][qh][u] + pt[3][qh][u]
            + pt[4][qh][u] + pt[5][qh][u] + pt[6][qh][u] + pt[7][qh][u];
    float oo = s + b_out[u];
    out[((size_t)(b * TQ + qabs0 + qh)) * OUTSZ + u] = fast_tanh(oo);
  }
}

// ---------------- round-6-style fallback (ws too small) ----------------------
__device__ __forceinline__ float sc4f(float4 w, float4 k, float4 a, float acc) {
  acc = fmaf(w.x, RCPF(EXP2F(fmaf(k.x, K2E, a.x)) + 1.0f), acc);
  acc = fmaf(w.y, RCPF(EXP2F(fmaf(k.y, K2E, a.y)) + 1.0f), acc);
  acc = fmaf(w.z, RCPF(EXP2F(fmaf(k.z, K2E, a.z)) + 1.0f), acc);
  acc = fmaf(w.w, RCPF(EXP2F(fmaf(k.w, K2E, a.w)) + 1.0f), acc);
  return acc;
}

__global__ __launch_bounds__(1024, 4)
void attn_fallback(const float* __restrict__ query, const float* __restrict__ keys,
                   const float* __restrict__ values, const float* __restrict__ W_q,
                   const float* __restrict__ b_q, const float* __restrict__ w_att,
                   const float* __restrict__ b_att, const float* __restrict__ W_out,
                   const float* __restrict__ b_out,
                   float* __restrict__ out, float* __restrict__ probs)
{
  __shared__ __align__(16) float qv[2][NN];
  __shared__ __align__(16) float aqc[2][NN];
  __shared__ __align__(16) float wv[NN];
  __shared__ __align__(16) float pr[2][TK];
  __shared__ __align__(16) float ctx[2][NN];
  __shared__ __align__(16) float part[2][2][NN];
  __shared__ float redm[2][8], reds[2][8], redw[8];

  const int t = threadIdx.x, H = t >> 9, u = t & 511;
  const int wave = t >> 6, lane = t & 63, wq8 = wave & 7;
  const int p = blockIdx.x, b = (p & 7) >> 1;
  const int qg = ((p >> 3) << 1) | (p & 1), qabs0 = qg * 2;
  const float batt = b_att[0];

  if (H == 0) wv[u] = w_att[u];
  qv[H][u] = query[((size_t)(b * TQ + qabs0 + H)) * NN + u];
  __syncthreads();
  if (H == 0) {
    float wp = waveRedSum(wv[u]);
    if (lane == 0) redw[wq8] = wp;
  }
  __syncthreads();
  const float sumW = redw[0]+redw[1]+redw[2]+redw[3]+redw[4]+redw[5]+redw[6]+redw[7];

  {
    const float4* wq4 = (const float4*)(W_q + (size_t)u * NN + 256 * H);
    const float4* x4  = (const float4*)(qv[0] + 256 * H);
    const float4* y4  = (const float4*)(qv[1] + 256 * H);
    float a0=0.f, a0b=0.f, a1=0.f, a1b=0.f;
    #pragma unroll 2
    for (int c = 0; c < 16; ++c) {
      float4 wA=wq4[4*c+0], wB=wq4[4*c+1], wC=wq4[4*c+2], wD=wq4[4*c+3];
      float4 xA=x4[4*c+0], xB=x4[4*c+1], xC=x4[4*c+2], xD=x4[4*c+3];
      a0 = fma4(wA,xA,a0); a0b = fma4(wB,xB,a0b);
      a0 = fma4(wC,xC,a0); a0b = fma4(wD,xD,a0b);
      float4 yA=y4[4*c+0], yB=y4[4*c+1], yC=y4[4*c+2], yD=y4[4*c+3];
      a1 = fma4(wA,yA,a1); a1b = fma4(wB,yB,a1b);
      a1 = fma4(wC,yC,a1); a1b = fma4(wD,yD,a1b);
    }
    part[H][0][u] = a0 + a0b; part[H][1][u] = a1 + a1b;
  }
  __syncthreads();
  aqc[H][u] = (part[0][H][u] + part[1][H][u] + b_q[u]) * K2E;
  __syncthreads();

  {
    const float4* kr  = (const float4*)(keys + ((size_t)(b * TK) + u) * NN + 256 * H);
    const float4* a0p = (const float4*)(aqc[0] + 256 * H);
    const float4* a1p = (const float4*)(aqc[1] + 256 * H);
    const float4* w4  = (const float4*)(wv + 256 * H);
    float s0 = 0.f, s1 = 0.f;
    #pragma unroll 2
    for (int c = 0; c < 16; ++c) {
      float4 kA=kr[4*c+0], kB=kr[4*c+1], kC=kr[4*c+2], kD=kr[4*c+3];
      float4 wA=w4[4*c+0], wB=w4[4*c+1], wC=w4[4*c+2], wD=w4[4*c+3];
      float4 aA=a0p[4*c+0], aB=a0p[4*c+1], aC=a0p[4*c+2], aD=a0p[4*c+3];
      s0 = sc4f(wA,kA,aA,s0); s0 = sc4f(wB,kB,aB,s0);
      s0 = sc4f(wC,kC,aC,s0); s0 = sc4f(wD,kD,aD,s0);
      float4 bA=a1p[4*c+0], bB=a1p[4*c+1], bC=a1p[4*c+2], bD=a1p[4*c+3];
      s1 = sc4f(wA,kA,bA,s1); s1 = sc4f(wB,kB,bB,s1);
      s1 = sc4f(wC,kC,bC,s1); s1 = sc4f(wD,kD,bD,s1);
    }
    part[H][0][u] = s0; part[H][1][u] = s1;
  }
  __syncthreads();

  {
    float sc = batt + sumW - 2.0f * (part[0][H][u] + part[1][H][u]);
    float m = waveRedMax(sc);
    if (lane == 0) redm[H][wq8] = m;
    __syncthreads();
    float bm = fmaxf(fmaxf(fmaxf(redm[H][0],redm[H][1]),fmaxf(redm[H][2],redm[H][3])),
                     fmaxf(fmaxf(redm[H][4],redm[H][5]),fmaxf(redm[H][6],redm[H][7])));
    float e = EXP2F((sc - bm) * L2E);
    float se = waveRedSum(e);
    if (lane == 0) reds[H][wq8] = se;
    __syncthreads();
    float bs = reds[H][0]+reds[H][1]+reds[H][2]+reds[H][3]
             + reds[H][4]+reds[H][5]+reds[H][6]+reds[H][7];
    float pv = e * RCPF(bs);
    pr[H][u] = pv;
    probs[((size_t)(b * TQ + qabs0 + H)) * TK + u] = pv;
  }
  __syncthreads();

  {
    const float* vcol = values + ((size_t)(b * TK) + 256 * H) * NN + u;
    const float4* p0 = (const float4*)(pr[0] + 256 * H);
    const float4* p1 = (const float4*)(pr[1] + 256 * H);
    float c0a=0.f, c0b=0.f, c1a=0.f, c1b=0.f;
    #pragma unroll 2
    for (int k = 0; k < 256; k += 8) {
      float v0 = vcol[(size_t)(k+0)*NN]; float v1 = vcol[(size_t)(k+1)*NN];
      float v2 = vcol[(size_t)(k+2)*NN]; float v3 = vcol[(size_t)(k+3)*NN];
      float v4 = vcol[(size_t)(k+4)*NN]; float v5 = vcol[(size_t)(k+5)*NN];
      float v6 = vcol[(size_t)(k+6)*NN]; float v7 = vcol[(size_t)(k+7)*NN];
      float4 pA = p0[k>>2], pB = p0[(k>>2)+1];
      float4 qA = p1[k>>2], qB = p1[(k>>2)+1];
      c0a = fmaf(pA.x,v0,c0a); c0a = fmaf(pA.y,v1,c0a);
      c0b = fmaf(pA.z,v2,c0b); c0b = fmaf(pA.w,v3,c0b);
      c0a = fmaf(pB.x,v4,c0a); c0a = fmaf(pB.y,v5,c0a);
      c0b = fmaf(pB.z,v6,c0b); c0b = fmaf(pB.w,v7,c0b);
      c1a = fmaf(qA.x,v0,c1a); c1a = fmaf(qA.y,v1,c1a);
      c1b = fmaf(qA.z,v2,c1b); c1b = fmaf(qA.w,v3,c1b);
      c1a = fmaf(qB.x,v4,c1a); c1a = fmaf(qB.y,v5,c1a);
      c1b = fmaf(qB.z,v6,c1b); c1b = fmaf(qB.w,v7,c1b);
    }
    part[H][0][u] = c0a + c0b; part[H][1][u] = c1a + c1b;
  }
  __syncthreads();
  ctx[H][u] = part[0][H][u] + part[1][H][u];
  __syncthreads();

  {
    const float4* wo = (const float4*)(W_out + (size_t)u * CATSZ + 512 * H);
    const float4* x4 = (H == 0) ? (const float4*)qv[0] : (const float4*)ctx[0];
    const float4* y4 = (H == 0) ? (const float4*)qv[1] : (const float4*)ctx[1];
    float o0=0.f, o0b=0.f, o1=0.f, o1b=0.f;
    #pragma unroll 2
    for (int c = 0; c < 32; ++c) {
      float4 wA=wo[4*c+0], wB=wo[4*c+1], wC=wo[4*c+2], wD=wo[4*c+3];
      float4 xA=x4[4*c+0], xB=x4[4*c+1], xC=x4[4*c+2], xD=x4[4*c+3];
      o0 = fma4(wA,xA,o0); o0b = fma4(wB,xB,o0b);
      o0 = fma4(wC,xC,o0); o0b = fma4(wD,xD,o0b);
      float4 yA=y4[4*c+0], yB=y4[4*c+1], yC=y4[4*c+2], yD=y4[4*c+3];
      o1 = fma4(wA,yA,o1); o1b = fma4(wB,yB,o1b);
      o1 = fma4(wC,yC,o1); o1b = fma4(wD,yD,o1b);
    }
    part[H][0][u] = o0 + o0b; part[H][1][u] = o1 + o1b;
  }
  __syncthreads();
  {
    float oo = part[0][H][u] + part[1][H][u] + b_out[u];
    out[((size_t)(b * TQ + qabs0 + H)) * OUTSZ + u] = fast_tanh(oo);
  }
}

extern "C" void kernel_launch(void* const* d_in, const int* in_sizes, int n_in,
                              void* d_out, int out_size, void* d_ws, size_t ws_size,
                              hipStream_t stream) {
  const float* query = (const float*)d_in[0];
  const float* keys  = (const float*)d_in[1];
  const float* vals  = (const float*)d_in[2];
  const float* W_q   = (const float*)d_in[3];
  const float* b_q   = (const float*)d_in[4];
  const float* w_att = (const float*)d_in[5];
  const float* b_att = (const float*)d_in[6];
  const float* W_out = (const float*)d_in[7];
  const float* b_out = (const float*)d_in[8];

  float* out   = (float*)d_out;
  float* probs = out + (size_t)BB * TQ * OUTSZ;

  if (ws_size >= (size_t)WS_HALVES * sizeof(_Float16)) {
    _Float16* ws = (_Float16*)d_ws;
    pack_kernel<<<dim3(2304), dim3(256), 0, stream>>>(keys, W_q, W_out, vals, ws);
    attn_main<<<dim3(BB * TQ / 2), dim3(1024), 0, stream>>>(
        query, b_q, w_att, b_att, b_out, ws, out, probs);
  } else {
    attn_fallback<<<dim3(BB * TQ / 2), dim3(1024), 0, stream>>>(
        query, keys, vals, W_q, b_q, w_att, b_att, W_out, b_out, out, probs);
  }
}

// Round 10
// 117.337 us; speedup vs baseline: 8.9399x; 1.1100x over previous
//
#include <hip/hip_runtime.h>
#include <hip/hip_fp16.h>

// Shape: b=4, t_q=128, t_k=512, n=512, out=512. All fp32 in/out.
// Output: [out (4*128*512), probs (4*128*512)].
//
// Round-10: round-9 was a balanced VALU+LDS+barrier mix. This round halves
// VALU in the dot-product stages (1/4/5) with v_dot2_f32_f16 (fdot2):
// weights/values repacked PAIR-INTERLEAVED fp16 (P[c/2][out][2]) so one
// 16B load = 4 outputs x 2 contraction elems; LDS broadcast operand is one
// b64 per 2 contraction steps. Step 2 (sigmoid) keeps quad form, unroll 8
// for more outstanding loads. keysE layout unchanged.

#define BB    4
#define TQ    128
#define TK    512
#define NN    512
#define OUTSZ 512
#define CATSZ 1024
#define K2E   2.8853900817779268f   // 2*log2(e)
#define L2E   1.4426950408889634f   // log2(e)
#define MAT   262144                // 512*512
// ws halves: keysE[0,4M) W_qP[4M,5M) W_outP[5M,7M) valuesP[7M,11M)
#define WS_HALVES (11 * MAT)

typedef __attribute__((ext_vector_type(4))) _Float16 half4;
typedef __attribute__((ext_vector_type(2))) _Float16 h2;

#if __has_builtin(__builtin_amdgcn_exp2f)
#define EXP2F(x) __builtin_amdgcn_exp2f(x)
#else
#define EXP2F(x) exp2f(x)
#endif
#if __has_builtin(__builtin_amdgcn_rcpf)
#define RCPF(x) __builtin_amdgcn_rcpf(x)
#else
#define RCPF(x) (1.0f / (x))
#endif

__device__ __forceinline__ h2 u2h(unsigned int u) {
  union { unsigned int i; h2 h; } v; v.i = u; return v.h;
}
#if __has_builtin(__builtin_amdgcn_fdot2)
__device__ __forceinline__ float FDOT2(h2 a, h2 b, float c) {
  return __builtin_amdgcn_fdot2(a, b, c, false);
}
#else
__device__ __forceinline__ float FDOT2(h2 a, h2 b, float c) {
  return fmaf((float)a.x, (float)b.x, fmaf((float)a.y, (float)b.y, c));
}
#endif

__device__ __forceinline__ float fast_tanh(float x) {
  float e = EXP2F(x * K2E);
  return fmaf(-2.0f, RCPF(e + 1.0f), 1.0f);
}
__device__ __forceinline__ float waveRedSum(float s) {
  #pragma unroll
  for (int m = 32; m >= 1; m >>= 1) s += __shfl_xor(s, m, 64);
  return s;
}
__device__ __forceinline__ float waveRedMax(float s) {
  #pragma unroll
  for (int m = 32; m >= 1; m >>= 1) s = fmaxf(s, __shfl_xor(s, m, 64));
  return s;
}
__device__ __forceinline__ float fma4(float4 w, float4 v, float acc) {
  acc = fmaf(w.x, v.x, acc); acc = fmaf(w.y, v.y, acc);
  acc = fmaf(w.z, v.z, acc); acc = fmaf(w.w, v.w, acc);
  return acc;
}
// score quad: s[i] += w * rcp(E_h[i]*A + 1)
__device__ __forceinline__ float4 scqh(float4 s, half4 E, float A, float w) {
  s.x = fmaf(w, RCPF(fmaf((float)E.x, A, 1.0f)), s.x);
  s.y = fmaf(w, RCPF(fmaf((float)E.y, A, 1.0f)), s.y);
  s.z = fmaf(w, RCPF(fmaf((float)E.z, A, 1.0f)), s.z);
  s.w = fmaf(w, RCPF(fmaf((float)E.w, A, 1.0f)), s.w);
  return s;
}
// paired-GEMM micro-op: 8 fdot2 for 4 outputs x 2 rows, one contraction pair
__device__ __forceinline__ void dotq(float4& r0, float4& r1, uint4 wp, uint2 cp) {
  h2 c0 = u2h(cp.x), c1 = u2h(cp.y);
  r0.x = FDOT2(u2h(wp.x), c0, r0.x); r1.x = FDOT2(u2h(wp.x), c1, r1.x);
  r0.y = FDOT2(u2h(wp.y), c0, r0.y); r1.y = FDOT2(u2h(wp.y), c1, r1.y);
  r0.z = FDOT2(u2h(wp.z), c0, r0.z); r1.z = FDOT2(u2h(wp.z), c1, r1.z);
  r0.w = FDOT2(u2h(wp.w), c0, r0.w); r1.w = FDOT2(u2h(wp.w), c1, r1.w);
}

// ---------------- pack kernel ------------------------------------------------
// keysE[b][n][k] = (fp16) exp2(K2E*keys[b][k][n])                [0, 4M)
// W_qP[(d>>1)*1024 + n*2 + (d&1)]  = (fp16) W_q[n][d]            [4M, 5M)
// W_outP[(c>>1)*1024 + o*2 + (c&1)] = (fp16) W_out[o][c]         [5M, 7M)
// valuesP[b*M + (k>>1)*1024 + n*2 + (k&1)] = (fp16) V[b][k][n]   [7M, 11M)
__global__ __launch_bounds__(256)
void pack_kernel(const float* __restrict__ keys, const float* __restrict__ W_q,
                 const float* __restrict__ W_out, const float* __restrict__ values,
                 _Float16* __restrict__ ws)
{
  __shared__ float tile[32][33];
  const int idx = blockIdx.x;
  const int tx = threadIdx.x & 31, ty = threadIdx.x >> 5;   // 32x8

  if (idx >= 1792) {                      // valuesP: 1024 blocks, 2 k-rows each
    int r = idx - 1792;
    int b = r >> 8, k2 = r & 255;
    const float* r0 = values + ((size_t)b * 512 + 2 * k2) * 512;
    const float* r1 = r0 + 512;
    int n0 = threadIdx.x * 2;
    float2 a = *(const float2*)(r0 + n0);
    float2 c = *(const float2*)(r1 + n0);
    _Float16* dst = ws + (size_t)7 * MAT + (size_t)b * MAT + k2 * 1024 + n0 * 2;
    half4 h = {(_Float16)a.x, (_Float16)c.x, (_Float16)a.y, (_Float16)c.y};
    *(half4*)dst = h;
    return;
  }

  if (idx < 1024) {                       // keysE: transpose + exp2
    int b = idx >> 8, r = idx & 255;
    int by = r >> 4, bx = r & 15;
    const float* src = keys + (size_t)b * MAT;
    _Float16* dst = ws + (size_t)b * MAT;
    #pragma unroll
    for (int i = 0; i < 32; i += 8)
      tile[ty + i][tx] = src[(size_t)(by * 32 + ty + i) * 512 + bx * 32 + tx] * K2E;
    __syncthreads();
    #pragma unroll
    for (int i = 0; i < 32; i += 8)
      dst[(size_t)(bx * 32 + ty + i) * 512 + by * 32 + tx] = (_Float16)EXP2F(tile[tx][ty + i]);
    return;
  }

  // paired transposes
  const float* src; _Float16* dst; int N; int by, bx;
  if (idx < 1280) {                       // W_qP
    int r = idx - 1024; by = r >> 4; bx = r & 15;
    src = W_q; dst = ws + (size_t)4 * MAT; N = 512;
  } else {                                // W_outP
    int r = idx - 1280; by = r >> 5; bx = r & 31;
    src = W_out; dst = ws + (size_t)5 * MAT; N = 1024;
  }
  #pragma unroll
  for (int i = 0; i < 32; i += 8)
    tile[ty + i][tx] = src[(size_t)(by * 32 + ty + i) * N + bx * 32 + tx];
  __syncthreads();
  #pragma unroll
  for (int i = 0; i < 32; i += 8) {
    int d = bx * 32 + ty + i;             // contraction index (d or c)
    int o = by * 32 + tx;                 // output index (n or o)
    dst[(size_t)(d >> 1) * 1024 + o * 2 + (d & 1)] = (_Float16)tile[tx][ty + i];
  }
}

// ---------------- main kernel ------------------------------------------------
__global__ __launch_bounds__(1024, 4)
void attn_main(const float* __restrict__ query,
               const float* __restrict__ b_q, const float* __restrict__ w_att,
               const float* __restrict__ b_att, const float* __restrict__ b_out,
               const _Float16* __restrict__ ws,
               float* __restrict__ out, float* __restrict__ probs)
{
  // catH[(c>>1)*4 + row*2 + (c&1)]: c in [0,512) query, [512,1024) ctx
  __shared__ __align__(16) _Float16 catH[2048];   // 4 KB
  __shared__ __align__(16) float4 paw[NN];        // {A0, A1, w, pad} 8 KB
  __shared__ __align__(16) _Float16 prH[1024];    // probs pairs, 2 KB
  __shared__ __align__(16) float  pt[8][2][NN];   // partial scratch 32 KB
  __shared__ float redm[2][8], reds2[2][8], redw[8];

  const _Float16* wsKeys  = ws;
  const _Float16* wsWqP   = ws + (size_t)4 * MAT;
  const _Float16* wsWoutP = ws + (size_t)5 * MAT;
  const _Float16* wsValP  = ws + (size_t)7 * MAT;

  const int t    = threadIdx.x;        // 0..1023
  const int qh   = t >> 9;             // combine-phase q row (0/1)
  const int u    = t & 511;            // combine-phase index
  const int G    = t >> 7;             // contraction range 0..7 (wave-uniform)
  const int v    = t & 127;            // output quad index (4v..4v+3)
  const int wave = t >> 6, lane = t & 63, wq8 = wave & 7;

  const int p  = blockIdx.x;                 // 0..255 (XCD swizzle)
  const int b  = (p & 7) >> 1;
  const int qg = ((p >> 3) << 1) | (p & 1);
  const int qabs0 = qg * 2;

  const float batt = b_att[0];

  // ---- stage: query rows -> catH (fp16 pairs), w_att partial sum ----
  float w_own = 0.f;
  if (qh == 0) {
    float q0 = query[((size_t)(b * TQ + qabs0 + 0)) * NN + u];
    float q1 = query[((size_t)(b * TQ + qabs0 + 1)) * NN + u];
    catH[(u >> 1) * 4 + (u & 1)]     = (_Float16)q0;
    catH[(u >> 1) * 4 + 2 + (u & 1)] = (_Float16)q1;
  } else {
    w_own = w_att[u];
  }
  if (qh == 1) {
    float wp = waveRedSum(w_own);
    if (lane == 0) redw[wq8] = wp;
  }
  __syncthreads();
  const float sumW = redw[0]+redw[1]+redw[2]+redw[3]+redw[4]+redw[5]+redw[6]+redw[7];

  // ---- step 1: att_q partials via fdot2.  Thread (G,v): n quad 4v, d2 in [32G,+32).
  {
    const _Float16* wq = wsWqP + 8 * v;
    float4 a0 = {0,0,0,0}, a1 = {0,0,0,0};
    #pragma unroll 4
    for (int j2 = 0; j2 < 32; ++j2) {
      int d2 = 32 * G + j2;
      uint4 wp = *(const uint4*)(wq + (size_t)d2 * 1024);
      uint2 cp = *(const uint2*)(&catH[d2 * 4]);
      dotq(a0, a1, wp, cp);
    }
    *(float4*)(&pt[G][0][4 * v]) = a0;
    *(float4*)(&pt[G][1][4 * v]) = a1;
  }
  __syncthreads();
  // combine: thread (qh,u): A = exp2(K2E * att_q); build paw
  {
    float s = pt[0][qh][u] + pt[1][qh][u] + pt[2][qh][u] + pt[3][qh][u]
            + pt[4][qh][u] + pt[5][qh][u] + pt[6][qh][u] + pt[7][qh][u];
    float A = EXP2F(K2E * (s + b_q[u]));
    if (qh == 0) { paw[u].x = A; paw[u].z = w_att[u]; }
    else         { paw[u].y = A; }
  }
  __syncthreads();

  // ---- step 2 (hot): score partials.  Thread (G,v): k quad 4v, n in [64G,+64).
  {
    const _Float16* ke = wsKeys + (size_t)b * MAT + 4 * v;
    float4 s0 = {0,0,0,0}, s1 = {0,0,0,0};
    #pragma unroll 8
    for (int j = 0; j < 64; ++j) {
      int n = 64 * G + j;
      half4 E   = *(const half4*)(ke + (size_t)n * 512);
      float4 pw = paw[n];
      s0 = scqh(s0, E, pw.x, pw.z);
      s1 = scqh(s1, E, pw.y, pw.z);
    }
    *(float4*)(&pt[G][0][4 * v]) = s0;
    *(float4*)(&pt[G][1][4 * v]) = s1;
  }
  __syncthreads();

  // ---- softmax: thread (qh,u) owns q=qh, k=u.
  {
    float s = pt[0][qh][u] + pt[1][qh][u] + pt[2][qh][u] + pt[3][qh][u]
            + pt[4][qh][u] + pt[5][qh][u] + pt[6][qh][u] + pt[7][qh][u];
    float sc = batt + sumW - 2.0f * s;
    float m = waveRedMax(sc);
    if (lane == 0) redm[qh][wq8] = m;
    __syncthreads();
    float bm = fmaxf(fmaxf(fmaxf(redm[qh][0],redm[qh][1]),fmaxf(redm[qh][2],redm[qh][3])),
                     fmaxf(fmaxf(redm[qh][4],redm[qh][5]),fmaxf(redm[qh][6],redm[qh][7])));
    float e = EXP2F((sc - bm) * L2E);
    float se = waveRedSum(e);
    if (lane == 0) reds2[qh][wq8] = se;
    __syncthreads();
    float bs = reds2[qh][0]+reds2[qh][1]+reds2[qh][2]+reds2[qh][3]
             + reds2[qh][4]+reds2[qh][5]+reds2[qh][6]+reds2[qh][7];
    float pv = e * RCPF(bs);
    prH[(u >> 1) * 4 + qh * 2 + (u & 1)] = (_Float16)pv;
    probs[((size_t)(b * TQ + qabs0 + qh)) * TK + u] = pv;
  }
  __syncthreads();

  // ---- step 4: context partials via fdot2.  Thread (G,v): n quad 4v, k2 in [32G,+32).
  {
    const _Float16* vp = wsValP + (size_t)b * MAT + 8 * v;
    float4 c0 = {0,0,0,0}, c1 = {0,0,0,0};
    #pragma unroll 4
    for (int j2 = 0; j2 < 32; ++j2) {
      int k2 = 32 * G + j2;
      uint4 vk = *(const uint4*)(vp + (size_t)k2 * 1024);
      uint2 pp = *(const uint2*)(&prH[k2 * 4]);
      dotq(c0, c1, vk, pp);
    }
    *(float4*)(&pt[G][0][4 * v]) = c0;
    *(float4*)(&pt[G][1][4 * v]) = c1;
  }
  __syncthreads();
  {
    float s = pt[0][qh][u] + pt[1][qh][u] + pt[2][qh][u] + pt[3][qh][u]
            + pt[4][qh][u] + pt[5][qh][u] + pt[6][qh][u] + pt[7][qh][u];
    catH[(256 + (u >> 1)) * 4 + qh * 2 + (u & 1)] = (_Float16)s;
  }
  __syncthreads();

  // ---- step 5: out partials via fdot2.  Thread (G,v): o quad 4v, c2 in [64G,+64).
  {
    const _Float16* wo = wsWoutP + 8 * v;
    float4 o0 = {0,0,0,0}, o1 = {0,0,0,0};
    #pragma unroll 4
    for (int j2 = 0; j2 < 64; ++j2) {
      int c2 = 64 * G + j2;
      uint4 wp = *(const uint4*)(wo + (size_t)c2 * 1024);
      uint2 cp = *(const uint2*)(&catH[c2 * 4]);
      dotq(o0, o1, wp, cp);
    }
    *(float4*)(&pt[G][0][4 * v]) = o0;
    *(float4*)(&pt[G][1][4 * v]) = o1;
  }
  __syncthreads();
  {
    float s = pt[0][qh][u] + pt[1][qh][u] + pt[2][qh][u] + pt[3][qh][u]
            + pt[4][qh][u] + pt[5][qh][u] + pt[6][qh][u] + pt[7][qh][u];
    float oo = s + b_out[u];
    out[((size_t)(b * TQ + qabs0 + qh)) * OUTSZ + u] = fast_tanh(oo);
  }
}

// ---------------- round-6-style fallback (ws too small) ----------------------
__device__ __forceinline__ float sc4f(float4 w, float4 k, float4 a, float acc) {
  acc = fmaf(w.x, RCPF(EXP2F(fmaf(k.x, K2E, a.x)) + 1.0f), acc);
  acc = fmaf(w.y, RCPF(EXP2F(fmaf(k.y, K2E, a.y)) + 1.0f), acc);
  acc = fmaf(w.z, RCPF(EXP2F(fmaf(k.z, K2E, a.z)) + 1.0f), acc);
  acc = fmaf(w.w, RCPF(EXP2F(fmaf(k.w, K2E, a.w)) + 1.0f), acc);
  return acc;
}

__global__ __launch_bounds__(1024, 4)
void attn_fallback(const float* __restrict__ query, const float* __restrict__ keys,
                   const float* __restrict__ values, const float* __restrict__ W_q,
                   const float* __restrict__ b_q, const float* __restrict__ w_att,
                   const float* __restrict__ b_att, const float* __restrict__ W_out,
                   const float* __restrict__ b_out,
                   float* __restrict__ out, float* __restrict__ probs)
{
  __shared__ __align__(16) float qv[2][NN];
  __shared__ __align__(16) float aqc[2][NN];
  __shared__ __align__(16) float wv[NN];
  __shared__ __align__(16) float pr[2][TK];
  __shared__ __align__(16) float ctx[2][NN];
  __shared__ __align__(16) float part[2][2][NN];
  __shared__ float redm[2][8], reds[2][8], redw[8];

  const int t = threadIdx.x, H = t >> 9, u = t & 511;
  const int wave = t >> 6, lane = t & 63, wq8 = wave & 7;
  const int p = blockIdx.x, b = (p & 7) >> 1;
  const int qg = ((p >> 3) << 1) | (p & 1), qabs0 = qg * 2;
  const float batt = b_att[0];

  if (H == 0) wv[u] = w_att[u];
  qv[H][u] = query[((size_t)(b * TQ + qabs0 + H)) * NN + u];
  __syncthreads();
  if (H == 0) {
    float wp = waveRedSum(wv[u]);
    if (lane == 0) redw[wq8] = wp;
  }
  __syncthreads();
  const float sumW = redw[0]+redw[1]+redw[2]+redw[3]+redw[4]+redw[5]+redw[6]+redw[7];

  {
    const float4* wq4 = (const float4*)(W_q + (size_t)u * NN + 256 * H);
    const float4* x4  = (const float4*)(qv[0] + 256 * H);
    const float4* y4  = (const float4*)(qv[1] + 256 * H);
    float a0=0.f, a0b=0.f, a1=0.f, a1b=0.f;
    #pragma unroll 2
    for (int c = 0; c < 16; ++c) {
      float4 wA=wq4[4*c+0], wB=wq4[4*c+1], wC=wq4[4*c+2], wD=wq4[4*c+3];
      float4 xA=x4[4*c+0], xB=x4[4*c+1], xC=x4[4*c+2], xD=x4[4*c+3];
      a0 = fma4(wA,xA,a0); a0b = fma4(wB,xB,a0b);
      a0 = fma4(wC,xC,a0); a0b = fma4(wD,xD,a0b);
      float4 yA=y4[4*c+0], yB=y4[4*c+1], yC=y4[4*c+2], yD=y4[4*c+3];
      a1 = fma4(wA,yA,a1); a1b = fma4(wB,yB,a1b);
      a1 = fma4(wC,yC,a1); a1b = fma4(wD,yD,a1b);
    }
    part[H][0][u] = a0 + a0b; part[H][1][u] = a1 + a1b;
  }
  __syncthreads();
  aqc[H][u] = (part[0][H][u] + part[1][H][u] + b_q[u]) * K2E;
  __syncthreads();

  {
    const float4* kr  = (const float4*)(keys + ((size_t)(b * TK) + u) * NN + 256 * H);
    const float4* a0p = (const float4*)(aqc[0] + 256 * H);
    const float4* a1p = (const float4*)(aqc[1] + 256 * H);
    const float4* w4  = (const float4*)(wv + 256 * H);
    float s0 = 0.f, s1 = 0.f;
    #pragma unroll 2
    for (int c = 0; c < 16; ++c) {
      float4 kA=kr[4*c+0], kB=kr[4*c+1], kC=kr[4*c+2], kD=kr[4*c+3];
      float4 wA=w4[4*c+0], wB=w4[4*c+1], wC=w4[4*c+2], wD=w4[4*c+3];
      float4 aA=a0p[4*c+0], aB=a0p[4*c+1], aC=a0p[4*c+2], aD=a0p[4*c+3];
      s0 = sc4f(wA,kA,aA,s0); s0 = sc4f(wB,kB,aB,s0);
      s0 = sc4f(wC,kC,aC,s0); s0 = sc4f(wD,kD,aD,s0);
      float4 bA=a1p[4*c+0], bB=a1p[4*c+1], bC=a1p[4*c+2], bD=a1p[4*c+3];
      s1 = sc4f(wA,kA,bA,s1); s1 = sc4f(wB,kB,bB,s1);
      s1 = sc4f(wC,kC,bC,s1); s1 = sc4f(wD,kD,bD,s1);
    }
    part[H][0][u] = s0; part[H][1][u] = s1;
  }
  __syncthreads();

  {
    float sc = batt + sumW - 2.0f * (part[0][H][u] + part[1][H][u]);
    float m = waveRedMax(sc);
    if (lane == 0) redm[H][wq8] = m;
    __syncthreads();
    float bm = fmaxf(fmaxf(fmaxf(redm[H][0],redm[H][1]),fmaxf(redm[H][2],redm[H][3])),
                     fmaxf(fmaxf(redm[H][4],redm[H][5]),fmaxf(redm[H][6],redm[H][7])));
    float e = EXP2F((sc - bm) * L2E);
    float se = waveRedSum(e);
    if (lane == 0) reds[H][wq8] = se;
    __syncthreads();
    float bs = reds[H][0]+reds[H][1]+reds[H][2]+reds[H][3]
             + reds[H][4]+reds[H][5]+reds[H][6]+reds[H][7];
    float pv = e * RCPF(bs);
    pr[H][u] = pv;
    probs[((size_t)(b * TQ + qabs0 + H)) * TK + u] = pv;
  }
  __syncthreads();

  {
    const float* vcol = values + ((size_t)(b * TK) + 256 * H) * NN + u;
    const float4* p0 = (const float4*)(pr[0] + 256 * H);
    const float4* p1 = (const float4*)(pr[1] + 256 * H);
    float c0a=0.f, c0b=0.f, c1a=0.f, c1b=0.f;
    #pragma unroll 2
    for (int k = 0; k < 256; k += 8) {
      float v0 = vcol[(size_t)(k+0)*NN]; float v1 = vcol[(size_t)(k+1)*NN];
      float v2 = vcol[(size_t)(k+2)*NN]; float v3 = vcol[(size_t)(k+3)*NN];
      float v4 = vcol[(size_t)(k+4)*NN]; float v5 = vcol[(size_t)(k+5)*NN];
      float v6 = vcol[(size_t)(k+6)*NN]; float v7 = vcol[(size_t)(k+7)*NN];
      float4 pA = p0[k>>2], pB = p0[(k>>2)+1];
      float4 qA = p1[k>>2], qB = p1[(k>>2)+1];
      c0a = fmaf(pA.x,v0,c0a); c0a = fmaf(pA.y,v1,c0a);
      c0b = fmaf(pA.z,v2,c0b); c0b = fmaf(pA.w,v3,c0b);
      c0a = fmaf(pB.x,v4,c0a); c0a = fmaf(pB.y,v5,c0a);
      c0b = fmaf(pB.z,v6,c0b); c0b = fmaf(pB.w,v7,c0b);
      c1a = fmaf(qA.x,v0,c1a); c1a = fmaf(qA.y,v1,c1a);
      c1b = fmaf(qA.z,v2,c1b); c1b = fmaf(qA.w,v3,c1b);
      c1a = fmaf(qB.x,v4,c1a); c1a = fmaf(qB.y,v5,c1a);
      c1b = fmaf(qB.z,v6,c1b); c1b = fmaf(qB.w,v7,c1b);
    }
    part[H][0][u] = c0a + c0b; part[H][1][u] = c1a + c1b;
  }
  __syncthreads();
  ctx[H][u] = part[0][H][u] + part[1][H][u];
  __syncthreads();

  {
    const float4* wo = (const float4*)(W_out + (size_t)u * CATSZ + 512 * H);
    const float4* x4 = (H == 0) ? (const float4*)qv[0] : (const float4*)ctx[0];
    const float4* y4 = (H == 0) ? (const float4*)qv[1] : (const float4*)ctx[1];
    float o0=0.f, o0b=0.f, o1=0.f, o1b=0.f;
    #pragma unroll 2
    for (int c = 0; c < 32; ++c) {
      float4 wA=wo[4*c+0], wB=wo[4*c+1], wC=wo[4*c+2], wD=wo[4*c+3];
      float4 xA=x4[4*c+0], xB=x4[4*c+1], xC=x4[4*c+2], xD=x4[4*c+3];
      o0 = fma4(wA,xA,o0); o0b = fma4(wB,xB,o0b);
      o0 = fma4(wC,xC,o0); o0b = fma4(wD,xD,o0b);
      float4 yA=y4[4*c+0], yB=y4[4*c+1], yC=y4[4*c+2], yD=y4[4*c+3];
      o1 = fma4(wA,yA,o1); o1b = fma4(wB,yB,o1b);
      o1 = fma4(wC,yC,o1); o1b = fma4(wD,yD,o1b);
    }
    part[H][0][u] = o0 + o0b; part[H][1][u] = o1 + o1b;
  }
  __syncthreads();
  {
    float oo = part[0][H][u] + part[1][H][u] + b_out[u];
    out[((size_t)(b * TQ + qabs0 + H)) * OUTSZ + u] = fast_tanh(oo);
  }
}

extern "C" void kernel_launch(void* const* d_in, const int* in_sizes, int n_in,
                              void* d_out, int out_size, void* d_ws, size_t ws_size,
                              hipStream_t stream) {
  const float* query = (const float*)d_in[0];
  const float* keys  = (const float*)d_in[1];
  const float* vals  = (const float*)d_in[2];
  const float* W_q   = (const float*)d_in[3];
  const float* b_q   = (const float*)d_in[4];
  const float* w_att = (const float*)d_in[5];
  const float* b_att = (const float*)d_in[6];
  const float* W_out = (const float*)d_in[7];
  const float* b_out = (const float*)d_in[8];

  float* out   = (float*)d_out;
  float* probs = out + (size_t)BB * TQ * OUTSZ;

  if (ws_size >= (size_t)WS_HALVES * sizeof(_Float16)) {
    _Float16* ws = (_Float16*)d_ws;
    pack_kernel<<<dim3(2816), dim3(256), 0, stream>>>(keys, W_q, W_out, vals, ws);
    attn_main<<<dim3(BB * TQ / 2), dim3(1024), 0, stream>>>(
        query, b_q, w_att, b_att, b_out, ws, out, probs);
  } else {
    attn_fallback<<<dim3(BB * TQ / 2), dim3(1024), 0, stream>>>(
        query, keys, vals, W_q, b_q, w_att, b_att, W_out, b_out, out, probs);
  }
}